// Round 2
// baseline (1606.572 us; speedup 1.0000x reference)
//
#include <hip/hip_runtime.h>
#include <math.h>

// ---------------------------------------------------------------------------
// GINE 2-layer GNN, N=100K nodes (D 32->64->64), E=3.2M edges, ED=16.
// Round 2: counting-sort edges by dst (hist/scan/scatter), then wave-per-node
// aggregation with register accumulation -> NO float atomics (was 800MB of
// atomic HBM write traffic per layer). ea materialized in sorted order when
// workspace allows. Node MLP + head kernels unchanged.
// ---------------------------------------------------------------------------

// ============================ sort pipeline ================================

__global__ __launch_bounds__(256) void k_hist(
    const int* __restrict__ dst, int* __restrict__ count, int E)
{
  for (int e = blockIdx.x * blockDim.x + threadIdx.x; e < E;
       e += gridDim.x * blockDim.x)
    atomicAdd(&count[dst[e]], 1);
}

// block-level exclusive scan: 256 threads x 4 elements = 1024/block
__global__ __launch_bounds__(256) void k_scan1(
    const int* __restrict__ cnt, int* __restrict__ exc,
    int* __restrict__ bsum, int M)
{
  __shared__ int wtot[4];
  const int t = threadIdx.x, lane = t & 63, wv = t >> 6;
  const int base = blockIdx.x * 1024 + t * 4;
  const int v0 = (base + 0 < M) ? cnt[base + 0] : 0;
  const int v1 = (base + 1 < M) ? cnt[base + 1] : 0;
  const int v2 = (base + 2 < M) ? cnt[base + 2] : 0;
  const int v3 = (base + 3 < M) ? cnt[base + 3] : 0;
  const int tsum = v0 + v1 + v2 + v3;
  int x = tsum;
#pragma unroll
  for (int off = 1; off < 64; off <<= 1) {
    const int y = __shfl_up(x, off, 64);
    if (lane >= off) x += y;
  }
  if (lane == 63) wtot[wv] = x;
  __syncthreads();
  int woff = 0;
#pragma unroll
  for (int w = 0; w < 4; ++w)
    if (w < wv) woff += wtot[w];
  int run = woff + x - tsum;  // exclusive prefix for this thread
  if (base + 0 < M) exc[base + 0] = run;
  run += v0;
  if (base + 1 < M) exc[base + 1] = run;
  run += v1;
  if (base + 2 < M) exc[base + 2] = run;
  run += v2;
  if (base + 3 < M) exc[base + 3] = run;
  if (t == 255) bsum[blockIdx.x] = woff + x;  // block total
}

__global__ void k_scan2(int* __restrict__ bsum, int nb)
{
  if (threadIdx.x == 0) {
    int r = 0;
    for (int i = 0; i < nb; ++i) { const int t = bsum[i]; bsum[i] = r; r += t; }
  }
}

__global__ __launch_bounds__(256) void k_scan3(
    int* __restrict__ start, int* __restrict__ cursor,
    const int* __restrict__ bsum, int M)
{
  for (int i = blockIdx.x * blockDim.x + threadIdx.x; i < M;
       i += gridDim.x * blockDim.x) {
    const int s = start[i] + bsum[i >> 10];
    start[i] = s;
    cursor[i] = s;
  }
}

__global__ __launch_bounds__(256) void k_scatter_mat(
    const int* __restrict__ src, const int* __restrict__ dst,
    const float4* __restrict__ ea4, int* __restrict__ cursor,
    int* __restrict__ srcs, float4* __restrict__ eas, int E)
{
  for (int e = blockIdx.x * blockDim.x + threadIdx.x; e < E;
       e += gridDim.x * blockDim.x) {
    const int d = dst[e];
    const int pos = atomicAdd(&cursor[d], 1);
    srcs[pos] = src[e];
    const float4 a = ea4[(size_t)e * 4 + 0];
    const float4 b = ea4[(size_t)e * 4 + 1];
    const float4 c = ea4[(size_t)e * 4 + 2];
    const float4 dd = ea4[(size_t)e * 4 + 3];
    eas[(size_t)pos * 4 + 0] = a;
    eas[(size_t)pos * 4 + 1] = b;
    eas[(size_t)pos * 4 + 2] = c;
    eas[(size_t)pos * 4 + 3] = dd;
  }
}

__global__ __launch_bounds__(256) void k_scatter_perm(
    const int* __restrict__ dst, int* __restrict__ cursor,
    int* __restrict__ perm, int E)
{
  for (int e = blockIdx.x * blockDim.x + threadIdx.x; e < E;
       e += gridDim.x * blockDim.x) {
    const int pos = atomicAdd(&cursor[dst[e]], 1);
    perm[pos] = e;
  }
}

// ===================== fused edge-embed + aggregate ========================
// MAT=true : EA = ea_sorted (indexed by sorted pos), SRCS = src_sorted
// MAT=false: EA = ea (orig), SRCS = src (orig), indexed via perm[]

template <bool MAT>
__global__ __launch_bounds__(256) void k_agg1(
    const float* __restrict__ x, const float* __restrict__ EA,
    const int* __restrict__ SRCS, const int* __restrict__ perm,
    const int* __restrict__ start, const float* __restrict__ We,
    const float* __restrict__ be, float* __restrict__ aggr, int N)
{
  const int lane = threadIdx.x & 63;
  const int j = lane & 31;     // output dim
  const int p = lane >> 5;     // edge parity (2 edges per wave-iter)
  float wcol[16];
#pragma unroll
  for (int k = 0; k < 16; ++k) wcol[k] = We[k * 32 + j];
  const float bias = be[j];
  const int wid = (blockIdx.x * blockDim.x + threadIdx.x) >> 6;
  const int nw = (gridDim.x * blockDim.x) >> 6;
  for (int d = wid; d < N; d += nw) {
    const int beg = start[d], end = start[d + 1];
    const int iters = (end - beg + 1) >> 1;
    float acc = 0.f;
    for (int ii = 0; ii < iters; ++ii) {
      const int i = beg + ii * 2 + p;
      const bool ok = i < end;
      const int ic = ok ? i : beg;
      const int ai = MAT ? ic : perm[ic];
      const float ev = (j < 16) ? EA[(size_t)ai * 16 + j] : 0.f;
      const int s = SRCS[ai];
      float em = bias;
#pragma unroll
      for (int k = 0; k < 16; ++k)
        em = fmaf(__shfl(ev, k, 32), wcol[k], em);
      const float xv = x[(size_t)s * 32 + j];
      acc += ok ? fmaxf(xv + em, 0.f) : 0.f;
    }
    acc += __shfl(acc, lane ^ 32, 64);  // combine the two halves
    if (lane < 32) aggr[(size_t)d * 32 + j] = acc;
  }
}

template <bool MAT>
__global__ __launch_bounds__(256) void k_agg2(
    const float* __restrict__ h1, const float* __restrict__ EA,
    const int* __restrict__ SRCS, const int* __restrict__ perm,
    const int* __restrict__ start, const float* __restrict__ We,
    const float* __restrict__ be, float* __restrict__ aggr, int N)
{
  const int lane = threadIdx.x & 63;
  float wcol[16];
#pragma unroll
  for (int k = 0; k < 16; ++k) wcol[k] = We[k * 64 + lane];
  const float bias = be[lane];
  const int wid = (blockIdx.x * blockDim.x + threadIdx.x) >> 6;
  const int nw = (gridDim.x * blockDim.x) >> 6;
  for (int d = wid; d < N; d += nw) {
    const int beg = start[d], end = start[d + 1];
    float acc = 0.f;
    int i = beg;
    int a0 = 0, s0 = 0;
    float ev0 = 0.f;
    if (i < end) {
      a0 = MAT ? i : perm[i];
      ev0 = (lane < 16) ? EA[(size_t)a0 * 16 + lane] : 0.f;
      s0 = SRCS[a0];
    }
    while (i < end) {  // software-pipelined: prefetch i+1 while computing i
      const int i1 = i + 1;
      int a1 = a0, s1 = s0;
      float ev1 = 0.f;
      if (i1 < end) {
        a1 = MAT ? i1 : perm[i1];
        ev1 = (lane < 16) ? EA[(size_t)a1 * 16 + lane] : 0.f;
        s1 = SRCS[a1];
      }
      const float hv = h1[(size_t)s0 * 64 + lane];
      float em = bias;
#pragma unroll
      for (int k = 0; k < 16; ++k)
        em = fmaf(__shfl(ev0, k, 64), wcol[k], em);
      acc += fmaxf(hv + em, 0.f);
      a0 = a1; ev0 = ev1; s0 = s1; i = i1;
    }
    aggr[(size_t)d * 64 + lane] = acc;
  }
}

// ===================== legacy atomic path (ws fallback) ====================

__global__ __launch_bounds__(256) void k_edge1(
    const float* __restrict__ x, const float* __restrict__ ea,
    const int* __restrict__ src, const int* __restrict__ dst,
    const float* __restrict__ We, const float* __restrict__ be,
    float* __restrict__ aggr, int E)
{
  const int lane = threadIdx.x & 31;
  float wcol[16];
#pragma unroll
  for (int k = 0; k < 16; ++k) wcol[k] = We[k * 32 + lane];
  const float bias = be[lane];
  const int gid = (blockIdx.x * blockDim.x + threadIdx.x) >> 5;
  const int ngrp = (gridDim.x * blockDim.x) >> 5;
  for (int e = gid; e < E; e += ngrp) {
    const int s = src[e], d = dst[e];
    const float eav = (lane < 16) ? ea[(size_t)e * 16 + lane] : 0.f;
    float acc = bias;
#pragma unroll
    for (int k = 0; k < 16; ++k) acc = fmaf(__shfl(eav, k, 32), wcol[k], acc);
    const float m = fmaxf(x[(size_t)s * 32 + lane] + acc, 0.f);
    atomicAdd(&aggr[(size_t)d * 32 + lane], m);
  }
}

__global__ __launch_bounds__(256) void k_edge2(
    const float* __restrict__ h1, const float* __restrict__ ea,
    const int* __restrict__ src, const int* __restrict__ dst,
    const float* __restrict__ We, const float* __restrict__ be,
    float* __restrict__ aggr, int E)
{
  const int lane = threadIdx.x & 63;
  float wcol[16];
#pragma unroll
  for (int k = 0; k < 16; ++k) wcol[k] = We[k * 64 + lane];
  const float bias = be[lane];
  const int gid = (blockIdx.x * blockDim.x + threadIdx.x) >> 6;
  const int ngrp = (gridDim.x * blockDim.x) >> 6;
  for (int e = gid; e < E; e += ngrp) {
    const int s = src[e], d = dst[e];
    const float eav = (lane < 16) ? ea[(size_t)e * 16 + lane] : 0.f;
    float acc = bias;
#pragma unroll
    for (int k = 0; k < 16; ++k) acc = fmaf(__shfl(eav, k, 64), wcol[k], acc);
    const float m = fmaxf(h1[(size_t)s * 64 + lane] + acc, 0.f);
    atomicAdd(&aggr[(size_t)d * 64 + lane], m);
  }
}

// ============================ node MLPs + head =============================

__global__ __launch_bounds__(256) void k_node1(
    const float* __restrict__ x, const float* __restrict__ aggr,
    const float* __restrict__ Wa, const float* __restrict__ ba,
    const float* __restrict__ Wb, const float* __restrict__ bb,
    float* __restrict__ h1, int N)
{
  const int lane = threadIdx.x & 63;
  float wa[32], wb[64];
#pragma unroll
  for (int k = 0; k < 32; ++k) wa[k] = Wa[k * 64 + lane];
#pragma unroll
  for (int k = 0; k < 64; ++k) wb[k] = Wb[k * 64 + lane];
  const float ba_l = ba[lane], bb_l = bb[lane];
  const int wid = (blockIdx.x * blockDim.x + threadIdx.x) >> 6;
  const int nw = (gridDim.x * blockDim.x) >> 6;
  for (int n = wid; n < N; n += nw) {
    const float hp =
        (lane < 32) ? (x[(size_t)n * 32 + lane] + aggr[(size_t)n * 32 + lane]) : 0.f;
    float t = ba_l;
#pragma unroll
    for (int k = 0; k < 32; ++k) t = fmaf(__shfl(hp, k, 64), wa[k], t);
    t = fmaxf(t, 0.f);
    float h = bb_l;
#pragma unroll
    for (int k = 0; k < 64; ++k) h = fmaf(__shfl(t, k, 64), wb[k], h);
    h1[(size_t)n * 64 + lane] = h;
  }
}

__global__ __launch_bounds__(256) void k_node2(
    const float* __restrict__ h1, const float* __restrict__ aggr,
    const float* __restrict__ Wa, const float* __restrict__ ba,
    const float* __restrict__ Wb, const float* __restrict__ bb,
    float* __restrict__ gsum, int N)
{
  const int lane = threadIdx.x & 63;
  const int wv = threadIdx.x >> 6;
  float wa[64], wb[64];
#pragma unroll
  for (int k = 0; k < 64; ++k) wa[k] = Wa[k * 64 + lane];
#pragma unroll
  for (int k = 0; k < 64; ++k) wb[k] = Wb[k * 64 + lane];
  const float ba_l = ba[lane], bb_l = bb[lane];
  float psum = 0.f;
  const int wid = (blockIdx.x * blockDim.x + threadIdx.x) >> 6;
  const int nw = (gridDim.x * blockDim.x) >> 6;
  for (int n = wid; n < N; n += nw) {
    const float hp = h1[(size_t)n * 64 + lane] + aggr[(size_t)n * 64 + lane];
    float t = ba_l;
#pragma unroll
    for (int k = 0; k < 64; ++k) t = fmaf(__shfl(hp, k, 64), wa[k], t);
    t = fmaxf(t, 0.f);
    float h = bb_l;
#pragma unroll
    for (int k = 0; k < 64; ++k) h = fmaf(__shfl(t, k, 64), wb[k], h);
    psum += h;
  }
  __shared__ float red[4][64];
  red[wv][lane] = psum;
  __syncthreads();
  if (threadIdx.x < 64) {
    const float s4 = red[0][lane] + red[1][lane] + red[2][lane] + red[3][lane];
    atomicAdd(&gsum[lane], s4);
  }
}

__global__ __launch_bounds__(256) void k_head(
    const float* __restrict__ gsum,
    const float* __restrict__ Wn1, const float* __restrict__ bn1,
    const float* __restrict__ Wn2, const float* __restrict__ bn2,
    const float* __restrict__ Ws1, const float* __restrict__ bs1,
    const float* __restrict__ Ws2, const float* __restrict__ bs2,
    const float* __restrict__ Wt1, const float* __restrict__ bt1,
    const float* __restrict__ Wt2, const float* __restrict__ bt2,
    float* __restrict__ out, float invN)
{
  __shared__ float g[64], z1[256], z2[128], sa[64], tb[64];
  const int t = threadIdx.x;
  if (t < 64) g[t] = gsum[t] * invN;
  __syncthreads();
  {
    float acc = bn1[t];
    for (int k = 0; k < 64; ++k) acc = fmaf(g[k], Wn1[k * 256 + t], acc);
    z1[t] = fmaxf(acc, 0.f);
  }
  __syncthreads();
  if (t < 128) {
    float acc = bn2[t];
    for (int k = 0; k < 256; ++k) acc = fmaf(z1[k], Wn2[k * 128 + t], acc);
    z2[t] = fmaxf(acc, 0.f);
  }
  __syncthreads();
  if (t < 64) {
    float acc = bs1[t];
    for (int k = 0; k < 128; ++k) acc = fmaf(z2[k], Ws1[k * 64 + t], acc);
    sa[t] = fmaxf(acc, 0.f);
  } else if (t < 128) {
    const int j = t - 64;
    float acc = bt1[j];
    for (int k = 0; k < 128; ++k) acc = fmaf(z2[k], Wt1[k * 64 + j], acc);
    tb[j] = fmaxf(acc, 0.f);
  }
  __syncthreads();
  if (t < 64) {
    float acc = bs2[t];
    for (int k = 0; k < 64; ++k) acc = fmaf(sa[k], Ws2[k * 64 + t], acc);
    out[t] = 1.f / (1.f + __expf(-acc));
  } else if (t < 96) {
    const int j = t - 64;
    float acc = bt2[j];
    for (int k = 0; k < 64; ++k) acc = fmaf(tb[k], Wt2[k * 32 + j], acc);
    out[64 + j] = 1.f / (1.f + __expf(-acc));
  }
}

// ================================ launch ===================================

extern "C" void kernel_launch(void* const* d_in, const int* in_sizes, int n_in,
                              void* d_out, int out_size, void* d_ws, size_t ws_size,
                              hipStream_t stream)
{
  const float* x   = (const float*)d_in[0];
  const float* ea  = (const float*)d_in[1];
  const int*   ei  = (const int*)d_in[2];
  const float* We1 = (const float*)d_in[3];  const float* be1 = (const float*)d_in[4];
  const float* W1a = (const float*)d_in[5];  const float* b1a = (const float*)d_in[6];
  const float* W1b = (const float*)d_in[7];  const float* b1b = (const float*)d_in[8];
  const float* We2 = (const float*)d_in[9];  const float* be2 = (const float*)d_in[10];
  const float* W2a = (const float*)d_in[11]; const float* b2a = (const float*)d_in[12];
  const float* W2b = (const float*)d_in[13]; const float* b2b = (const float*)d_in[14];
  const float* Wn1 = (const float*)d_in[15]; const float* bn1 = (const float*)d_in[16];
  const float* Wn2 = (const float*)d_in[17]; const float* bn2 = (const float*)d_in[18];
  const float* Ws1 = (const float*)d_in[19]; const float* bs1 = (const float*)d_in[20];
  const float* Ws2 = (const float*)d_in[21]; const float* bs2 = (const float*)d_in[22];
  const float* Wt1 = (const float*)d_in[23]; const float* bt1 = (const float*)d_in[24];
  const float* Wt2 = (const float*)d_in[25]; const float* bt2 = (const float*)d_in[26];

  const int N = in_sizes[0] / 32;
  const int E = in_sizes[1] / 16;
  const int* src = ei;
  const int* dst = ei + E;

  // -------- workspace layout --------
  char* ws = (char*)d_ws;
  size_t off = 0;
  auto alloc = [&](size_t bytes) -> char* {
    char* p = ws + off;
    off = (off + bytes + 255) & ~(size_t)255;
    return p;
  };
  float* h1     = (float*)alloc((size_t)N * 64 * 4);
  float* aggr   = (float*)alloc((size_t)N * 64 * 4);
  float* gsum   = (float*)alloc(256);
  int*   count  = (int*)alloc((size_t)(N + 1) * 4);
  int*   start  = (int*)alloc((size_t)(N + 1) * 4);
  int*   cursor = (int*)alloc((size_t)(N + 1) * 4);
  int*   bsum   = (int*)alloc(4096);
  int*   perm   = (int*)alloc((size_t)E * 4);
  const size_t base_need = off;
  int*   srcs = (int*)alloc((size_t)E * 4);
  float* eas  = (float*)alloc((size_t)E * 16 * 4);
  const size_t mat_need = off;

  const int mode = (ws_size >= mat_need) ? 2 : (ws_size >= base_need) ? 1 : 0;

  hipMemsetAsync(gsum, 0, 256, stream);

  if (mode == 0) {
    // legacy atomic fallback
    hipMemsetAsync(aggr, 0, (size_t)N * 32 * 4, stream);
    k_edge1<<<2048, 256, 0, stream>>>(x, ea, src, dst, We1, be1, aggr, E);
    k_node1<<<2048, 256, 0, stream>>>(x, aggr, W1a, b1a, W1b, b1b, h1, N);
    hipMemsetAsync(aggr, 0, (size_t)N * 64 * 4, stream);
    k_edge2<<<2048, 256, 0, stream>>>(h1, ea, src, dst, We2, be2, aggr, E);
  } else {
    const int M = N + 1;
    const int nb = (M + 1023) / 1024;
    const int egrid = min((E + 255) / 256, 8192);
    hipMemsetAsync(count, 0, (size_t)M * 4, stream);
    k_hist<<<egrid, 256, 0, stream>>>(dst, count, E);
    k_scan1<<<nb, 256, 0, stream>>>(count, start, bsum, M);
    k_scan2<<<1, 64, 0, stream>>>(bsum, nb);
    k_scan3<<<(M + 255) / 256, 256, 0, stream>>>(start, cursor, bsum, M);
    if (mode == 2) {
      k_scatter_mat<<<egrid, 256, 0, stream>>>(src, dst, (const float4*)ea,
                                               cursor, srcs, (float4*)eas, E);
      k_agg1<true><<<2048, 256, 0, stream>>>(x, eas, srcs, perm, start, We1, be1, aggr, N);
      k_node1<<<2048, 256, 0, stream>>>(x, aggr, W1a, b1a, W1b, b1b, h1, N);
      k_agg2<true><<<2048, 256, 0, stream>>>(h1, eas, srcs, perm, start, We2, be2, aggr, N);
    } else {
      k_scatter_perm<<<egrid, 256, 0, stream>>>(dst, cursor, perm, E);
      k_agg1<false><<<2048, 256, 0, stream>>>(x, ea, src, perm, start, We1, be1, aggr, N);
      k_node1<<<2048, 256, 0, stream>>>(x, aggr, W1a, b1a, W1b, b1b, h1, N);
      k_agg2<false><<<2048, 256, 0, stream>>>(h1, ea, src, perm, start, We2, be2, aggr, N);
    }
  }

  k_node2<<<2048, 256, 0, stream>>>(h1, aggr, W2a, b2a, W2b, b2b, gsum, N);
  k_head<<<1, 256, 0, stream>>>(gsum, Wn1, bn1, Wn2, bn2, Ws1, bs1, Ws2, bs2,
                                Wt1, bt1, Wt2, bt2, (float*)d_out, 1.f / (float)N);
}

// Round 3
// 1484.585 us; speedup vs baseline: 1.0822x; 1.0822x over previous
//
#include <hip/hip_runtime.h>
#include <math.h>

// ---------------------------------------------------------------------------
// GINE 2-layer GNN, N=100K nodes (D 32->64->64), E=3.2M edges, ED=16.
// Round 3: agg kernels restructured for latency: 4-edge blocks, float4 ea
// loads (coalesced 256B), wave-uniform scalar src loads, depth-1 software
// pipeline (prefetch next block's ea+src while computing current; h1/x
// gathers issued at block top, consumed after 4 independent FMA chains).
// ---------------------------------------------------------------------------

#define IMIN(a, b) ((a) < (b) ? (a) : (b))

// ============================ sort pipeline ================================

__global__ __launch_bounds__(256) void k_hist(
    const int* __restrict__ dst, int* __restrict__ count, int E)
{
  for (int e = blockIdx.x * blockDim.x + threadIdx.x; e < E;
       e += gridDim.x * blockDim.x)
    atomicAdd(&count[dst[e]], 1);
}

__global__ __launch_bounds__(256) void k_scan1(
    const int* __restrict__ cnt, int* __restrict__ exc,
    int* __restrict__ bsum, int M)
{
  __shared__ int wtot[4];
  const int t = threadIdx.x, lane = t & 63, wv = t >> 6;
  const int base = blockIdx.x * 1024 + t * 4;
  const int v0 = (base + 0 < M) ? cnt[base + 0] : 0;
  const int v1 = (base + 1 < M) ? cnt[base + 1] : 0;
  const int v2 = (base + 2 < M) ? cnt[base + 2] : 0;
  const int v3 = (base + 3 < M) ? cnt[base + 3] : 0;
  const int tsum = v0 + v1 + v2 + v3;
  int x = tsum;
#pragma unroll
  for (int off = 1; off < 64; off <<= 1) {
    const int y = __shfl_up(x, off, 64);
    if (lane >= off) x += y;
  }
  if (lane == 63) wtot[wv] = x;
  __syncthreads();
  int woff = 0;
#pragma unroll
  for (int w = 0; w < 4; ++w)
    if (w < wv) woff += wtot[w];
  int run = woff + x - tsum;
  if (base + 0 < M) exc[base + 0] = run;
  run += v0;
  if (base + 1 < M) exc[base + 1] = run;
  run += v1;
  if (base + 2 < M) exc[base + 2] = run;
  run += v2;
  if (base + 3 < M) exc[base + 3] = run;
  if (t == 255) bsum[blockIdx.x] = woff + x;
}

__global__ void k_scan2(int* __restrict__ bsum, int nb)
{
  if (threadIdx.x == 0) {
    int r = 0;
    for (int i = 0; i < nb; ++i) { const int t = bsum[i]; bsum[i] = r; r += t; }
  }
}

__global__ __launch_bounds__(256) void k_scan3(
    int* __restrict__ start, int* __restrict__ cursor,
    const int* __restrict__ bsum, int M)
{
  for (int i = blockIdx.x * blockDim.x + threadIdx.x; i < M;
       i += gridDim.x * blockDim.x) {
    const int s = start[i] + bsum[i >> 10];
    start[i] = s;
    cursor[i] = s;
  }
}

// 4 threads per edge: leader grabs slot, all 4 move one float4 each.
__global__ __launch_bounds__(256) void k_scatter4(
    const int* __restrict__ src, const int* __restrict__ dst,
    const float4* __restrict__ ea4, int* __restrict__ cursor,
    int* __restrict__ srcs, float4* __restrict__ eas, int E)
{
  const long tid0 = (long)blockIdx.x * blockDim.x + threadIdx.x;
  const long stride = (long)gridDim.x * blockDim.x;
  const int sub = threadIdx.x & 3;
  const long total = (long)E * 4;
  for (long t = tid0; t < total; t += stride) {
    const int e = (int)(t >> 2);
    int pos = 0;
    if (sub == 0) pos = atomicAdd(&cursor[dst[e]], 1);
    pos = __shfl(pos, 0, 4);
    if (sub == 0) srcs[pos] = src[e];
    eas[(size_t)pos * 4 + sub] = ea4[(size_t)e * 4 + sub];
  }
}

__global__ __launch_bounds__(256) void k_scatter_perm(
    const int* __restrict__ dst, int* __restrict__ cursor,
    int* __restrict__ perm, int E)
{
  for (int e = blockIdx.x * blockDim.x + threadIdx.x; e < E;
       e += gridDim.x * blockDim.x) {
    const int pos = atomicAdd(&cursor[dst[e]], 1);
    perm[pos] = e;
  }
}

// ===================== fused edge-embed + aggregate ========================
// 4-edge blocks. Lane l's float4 covers edge (i + ((l&15)>>2)), dims
// ((l&15)&3)*4.. ; broadcast via width-16 shfl. src via uniform s_load.

template <bool MAT>
__global__ __launch_bounds__(256) void k_agg2(
    const float* __restrict__ h1, const float* __restrict__ EA,
    const int* __restrict__ SRCS, const int* __restrict__ perm,
    const int* __restrict__ start, const float* __restrict__ We,
    const float* __restrict__ be, float* __restrict__ aggr, int N)
{
  const int lane = threadIdx.x & 63;
  const int g16 = lane & 15;
  const int cq = g16 >> 2;   // which of the 4 edges this lane loads
  const int cc = g16 & 3;    // which float4 of that edge
  float wcol[16];
#pragma unroll
  for (int k = 0; k < 16; ++k) wcol[k] = We[k * 64 + lane];
  const float bias = be[lane];
  const float4* EA4 = (const float4*)EA;
  const int wid = (blockIdx.x * blockDim.x + threadIdx.x) >> 6;
  const int nw = (gridDim.x * blockDim.x) >> 6;
  for (int d = wid; d < N; d += nw) {
    const int beg = __builtin_amdgcn_readfirstlane(start[d]);
    const int end = __builtin_amdgcn_readfirstlane(start[d + 1]);
    float acc = 0.f;
    if (beg < end) {
      const int em1 = end - 1;
      // ---- preload block 0 ----
      int el = IMIN(beg + cq, em1);
      int al = MAT ? el : perm[el];
      float4 ev = EA4[(size_t)al * 4 + cc];
      int e0 = beg, e1 = IMIN(beg + 1, em1), e2 = IMIN(beg + 2, em1), e3 = IMIN(beg + 3, em1);
      int s0 = SRCS[MAT ? e0 : perm[e0]];
      int s1 = SRCS[MAT ? e1 : perm[e1]];
      int s2 = SRCS[MAT ? e2 : perm[e2]];
      int s3 = SRCS[MAT ? e3 : perm[e3]];
      for (int i = beg; i < end; i += 4) {
        // 1. gathers for current block (s known from prefetch)
        const float hv0 = h1[(size_t)s0 * 64 + lane];
        const float hv1 = h1[(size_t)s1 * 64 + lane];
        const float hv2 = h1[(size_t)s2 * 64 + lane];
        const float hv3 = h1[(size_t)s3 * 64 + lane];
        // 2. prefetch next block
        const int inx = i + 4;
        float4 evn = ev;
        int t0 = s0, t1 = s1, t2 = s2, t3 = s3;
        if (inx < end) {
          const int eln = IMIN(inx + cq, em1);
          const int aln = MAT ? eln : perm[eln];
          evn = EA4[(size_t)aln * 4 + cc];
          const int f0 = inx, f1 = IMIN(inx + 1, em1), f2 = IMIN(inx + 2, em1), f3 = IMIN(inx + 3, em1);
          t0 = SRCS[MAT ? f0 : perm[f0]];
          t1 = SRCS[MAT ? f1 : perm[f1]];
          t2 = SRCS[MAT ? f2 : perm[f2]];
          t3 = SRCS[MAT ? f3 : perm[f3]];
        }
        // 3. four independent embedding chains
        float m0 = bias, m1 = bias, m2 = bias, m3 = bias;
#pragma unroll
        for (int k = 0; k < 16; ++k) {
          const int kc = k & 3, kr = k >> 2;
          const float c = kc == 0 ? ev.x : kc == 1 ? ev.y : kc == 2 ? ev.z : ev.w;
          m0 = fmaf(__shfl(c, 0 + kr, 16), wcol[k], m0);
          m1 = fmaf(__shfl(c, 4 + kr, 16), wcol[k], m1);
          m2 = fmaf(__shfl(c, 8 + kr, 16), wcol[k], m2);
          m3 = fmaf(__shfl(c, 12 + kr, 16), wcol[k], m3);
        }
        // 4. accumulate (guard tail)
        acc += fmaxf(hv0 + m0, 0.f);
        acc += (i + 1 < end) ? fmaxf(hv1 + m1, 0.f) : 0.f;
        acc += (i + 2 < end) ? fmaxf(hv2 + m2, 0.f) : 0.f;
        acc += (i + 3 < end) ? fmaxf(hv3 + m3, 0.f) : 0.f;
        // 5. shift
        ev = evn; s0 = t0; s1 = t1; s2 = t2; s3 = t3;
      }
    }
    aggr[(size_t)d * 64 + lane] = acc;
  }
}

template <bool MAT>
__global__ __launch_bounds__(256) void k_agg1(
    const float* __restrict__ x, const float* __restrict__ EA,
    const int* __restrict__ SRCS, const int* __restrict__ perm,
    const int* __restrict__ start, const float* __restrict__ We,
    const float* __restrict__ be, float* __restrict__ aggr, int N)
{
  const int lane = threadIdx.x & 63;
  const int j = lane & 31;   // output dim
  const int p = lane >> 5;   // half-wave: handles edges 2p, 2p+1 of each block
  const int g16 = lane & 15;
  const int cq = g16 >> 2;
  const int cc = g16 & 3;
  float wcol[16];
#pragma unroll
  for (int k = 0; k < 16; ++k) wcol[k] = We[k * 32 + j];
  const float bias = be[j];
  const float4* EA4 = (const float4*)EA;
  const int ba = p * 8;      // shfl base for chain a (edge 2p): (2p)*4
  const int bb = p * 8 + 4;  // chain b (edge 2p+1)
  const int wid = (blockIdx.x * blockDim.x + threadIdx.x) >> 6;
  const int nw = (gridDim.x * blockDim.x) >> 6;
  for (int d = wid; d < N; d += nw) {
    const int beg = __builtin_amdgcn_readfirstlane(start[d]);
    const int end = __builtin_amdgcn_readfirstlane(start[d + 1]);
    float acc = 0.f;
    if (beg < end) {
      const int em1 = end - 1;
      int el = IMIN(beg + cq, em1);
      int al = MAT ? el : perm[el];
      float4 ev = EA4[(size_t)al * 4 + cc];
      int e0 = beg, e1 = IMIN(beg + 1, em1), e2 = IMIN(beg + 2, em1), e3 = IMIN(beg + 3, em1);
      int s0 = SRCS[MAT ? e0 : perm[e0]];
      int s1 = SRCS[MAT ? e1 : perm[e1]];
      int s2 = SRCS[MAT ? e2 : perm[e2]];
      int s3 = SRCS[MAT ? e3 : perm[e3]];
      for (int i = beg; i < end; i += 4) {
        const int sa = p ? s2 : s0;
        const int sb = p ? s3 : s1;
        const float hva = x[(size_t)sa * 32 + j];
        const float hvb = x[(size_t)sb * 32 + j];
        const int inx = i + 4;
        float4 evn = ev;
        int t0 = s0, t1 = s1, t2 = s2, t3 = s3;
        if (inx < end) {
          const int eln = IMIN(inx + cq, em1);
          const int aln = MAT ? eln : perm[eln];
          evn = EA4[(size_t)aln * 4 + cc];
          const int f0 = inx, f1 = IMIN(inx + 1, em1), f2 = IMIN(inx + 2, em1), f3 = IMIN(inx + 3, em1);
          t0 = SRCS[MAT ? f0 : perm[f0]];
          t1 = SRCS[MAT ? f1 : perm[f1]];
          t2 = SRCS[MAT ? f2 : perm[f2]];
          t3 = SRCS[MAT ? f3 : perm[f3]];
        }
        float ma = bias, mb = bias;
#pragma unroll
        for (int k = 0; k < 16; ++k) {
          const int kc = k & 3, kr = k >> 2;
          const float c = kc == 0 ? ev.x : kc == 1 ? ev.y : kc == 2 ? ev.z : ev.w;
          ma = fmaf(__shfl(c, ba + kr, 16), wcol[k], ma);
          mb = fmaf(__shfl(c, bb + kr, 16), wcol[k], mb);
        }
        const int qa = i + p * 2, qb = i + p * 2 + 1;
        acc += (qa < end) ? fmaxf(hva + ma, 0.f) : 0.f;
        acc += (qb < end) ? fmaxf(hvb + mb, 0.f) : 0.f;
        ev = evn; s0 = t0; s1 = t1; s2 = t2; s3 = t3;
      }
    }
    acc += __shfl(acc, lane ^ 32, 64);
    if (lane < 32) aggr[(size_t)d * 32 + j] = acc;
  }
}

// ===================== legacy atomic path (ws fallback) ====================

__global__ __launch_bounds__(256) void k_edge1(
    const float* __restrict__ x, const float* __restrict__ ea,
    const int* __restrict__ src, const int* __restrict__ dst,
    const float* __restrict__ We, const float* __restrict__ be,
    float* __restrict__ aggr, int E)
{
  const int lane = threadIdx.x & 31;
  float wcol[16];
#pragma unroll
  for (int k = 0; k < 16; ++k) wcol[k] = We[k * 32 + lane];
  const float bias = be[lane];
  const int gid = (blockIdx.x * blockDim.x + threadIdx.x) >> 5;
  const int ngrp = (gridDim.x * blockDim.x) >> 5;
  for (int e = gid; e < E; e += ngrp) {
    const int s = src[e], d = dst[e];
    const float eav = (lane < 16) ? ea[(size_t)e * 16 + lane] : 0.f;
    float acc = bias;
#pragma unroll
    for (int k = 0; k < 16; ++k) acc = fmaf(__shfl(eav, k, 32), wcol[k], acc);
    const float m = fmaxf(x[(size_t)s * 32 + lane] + acc, 0.f);
    atomicAdd(&aggr[(size_t)d * 32 + lane], m);
  }
}

__global__ __launch_bounds__(256) void k_edge2(
    const float* __restrict__ h1, const float* __restrict__ ea,
    const int* __restrict__ src, const int* __restrict__ dst,
    const float* __restrict__ We, const float* __restrict__ be,
    float* __restrict__ aggr, int E)
{
  const int lane = threadIdx.x & 63;
  float wcol[16];
#pragma unroll
  for (int k = 0; k < 16; ++k) wcol[k] = We[k * 64 + lane];
  const float bias = be[lane];
  const int gid = (blockIdx.x * blockDim.x + threadIdx.x) >> 6;
  const int ngrp = (gridDim.x * blockDim.x) >> 6;
  for (int e = gid; e < E; e += ngrp) {
    const int s = src[e], d = dst[e];
    const float eav = (lane < 16) ? ea[(size_t)e * 16 + lane] : 0.f;
    float acc = bias;
#pragma unroll
    for (int k = 0; k < 16; ++k) acc = fmaf(__shfl(eav, k, 64), wcol[k], acc);
    const float m = fmaxf(h1[(size_t)s * 64 + lane] + acc, 0.f);
    atomicAdd(&aggr[(size_t)d * 64 + lane], m);
  }
}

// ============================ node MLPs + head =============================

__global__ __launch_bounds__(256) void k_node1(
    const float* __restrict__ x, const float* __restrict__ aggr,
    const float* __restrict__ Wa, const float* __restrict__ ba,
    const float* __restrict__ Wb, const float* __restrict__ bb,
    float* __restrict__ h1, int N)
{
  const int lane = threadIdx.x & 63;
  float wa[32], wb[64];
#pragma unroll
  for (int k = 0; k < 32; ++k) wa[k] = Wa[k * 64 + lane];
#pragma unroll
  for (int k = 0; k < 64; ++k) wb[k] = Wb[k * 64 + lane];
  const float ba_l = ba[lane], bb_l = bb[lane];
  const int wid = (blockIdx.x * blockDim.x + threadIdx.x) >> 6;
  const int nw = (gridDim.x * blockDim.x) >> 6;
  for (int n = wid; n < N; n += nw) {
    const float hp =
        (lane < 32) ? (x[(size_t)n * 32 + lane] + aggr[(size_t)n * 32 + lane]) : 0.f;
    float t = ba_l;
#pragma unroll
    for (int k = 0; k < 32; ++k) t = fmaf(__shfl(hp, k, 64), wa[k], t);
    t = fmaxf(t, 0.f);
    float h = bb_l;
#pragma unroll
    for (int k = 0; k < 64; ++k) h = fmaf(__shfl(t, k, 64), wb[k], h);
    h1[(size_t)n * 64 + lane] = h;
  }
}

__global__ __launch_bounds__(256) void k_node2(
    const float* __restrict__ h1, const float* __restrict__ aggr,
    const float* __restrict__ Wa, const float* __restrict__ ba,
    const float* __restrict__ Wb, const float* __restrict__ bb,
    float* __restrict__ gsum, int N)
{
  const int lane = threadIdx.x & 63;
  const int wv = threadIdx.x >> 6;
  float wa[64], wb[64];
#pragma unroll
  for (int k = 0; k < 64; ++k) wa[k] = Wa[k * 64 + lane];
#pragma unroll
  for (int k = 0; k < 64; ++k) wb[k] = Wb[k * 64 + lane];
  const float ba_l = ba[lane], bb_l = bb[lane];
  float psum = 0.f;
  const int wid = (blockIdx.x * blockDim.x + threadIdx.x) >> 6;
  const int nw = (gridDim.x * blockDim.x) >> 6;
  for (int n = wid; n < N; n += nw) {
    const float hp = h1[(size_t)n * 64 + lane] + aggr[(size_t)n * 64 + lane];
    float t = ba_l;
#pragma unroll
    for (int k = 0; k < 64; ++k) t = fmaf(__shfl(hp, k, 64), wa[k], t);
    t = fmaxf(t, 0.f);
    float h = bb_l;
#pragma unroll
    for (int k = 0; k < 64; ++k) h = fmaf(__shfl(t, k, 64), wb[k], h);
    psum += h;
  }
  __shared__ float red[4][64];
  red[wv][lane] = psum;
  __syncthreads();
  if (threadIdx.x < 64) {
    const float s4 = red[0][lane] + red[1][lane] + red[2][lane] + red[3][lane];
    atomicAdd(&gsum[lane], s4);
  }
}

__global__ __launch_bounds__(256) void k_head(
    const float* __restrict__ gsum,
    const float* __restrict__ Wn1, const float* __restrict__ bn1,
    const float* __restrict__ Wn2, const float* __restrict__ bn2,
    const float* __restrict__ Ws1, const float* __restrict__ bs1,
    const float* __restrict__ Ws2, const float* __restrict__ bs2,
    const float* __restrict__ Wt1, const float* __restrict__ bt1,
    const float* __restrict__ Wt2, const float* __restrict__ bt2,
    float* __restrict__ out, float invN)
{
  __shared__ float g[64], z1[256], z2[128], sa[64], tb[64];
  const int t = threadIdx.x;
  if (t < 64) g[t] = gsum[t] * invN;
  __syncthreads();
  {
    float acc = bn1[t];
    for (int k = 0; k < 64; ++k) acc = fmaf(g[k], Wn1[k * 256 + t], acc);
    z1[t] = fmaxf(acc, 0.f);
  }
  __syncthreads();
  if (t < 128) {
    float acc = bn2[t];
    for (int k = 0; k < 256; ++k) acc = fmaf(z1[k], Wn2[k * 128 + t], acc);
    z2[t] = fmaxf(acc, 0.f);
  }
  __syncthreads();
  if (t < 64) {
    float acc = bs1[t];
    for (int k = 0; k < 128; ++k) acc = fmaf(z2[k], Ws1[k * 64 + t], acc);
    sa[t] = fmaxf(acc, 0.f);
  } else if (t < 128) {
    const int j = t - 64;
    float acc = bt1[j];
    for (int k = 0; k < 128; ++k) acc = fmaf(z2[k], Wt1[k * 64 + j], acc);
    tb[j] = fmaxf(acc, 0.f);
  }
  __syncthreads();
  if (t < 64) {
    float acc = bs2[t];
    for (int k = 0; k < 64; ++k) acc = fmaf(sa[k], Ws2[k * 64 + t], acc);
    out[t] = 1.f / (1.f + __expf(-acc));
  } else if (t < 96) {
    const int j = t - 64;
    float acc = bt2[j];
    for (int k = 0; k < 64; ++k) acc = fmaf(tb[k], Wt2[k * 32 + j], acc);
    out[64 + j] = 1.f / (1.f + __expf(-acc));
  }
}

// ================================ launch ===================================

extern "C" void kernel_launch(void* const* d_in, const int* in_sizes, int n_in,
                              void* d_out, int out_size, void* d_ws, size_t ws_size,
                              hipStream_t stream)
{
  const float* x   = (const float*)d_in[0];
  const float* ea  = (const float*)d_in[1];
  const int*   ei  = (const int*)d_in[2];
  const float* We1 = (const float*)d_in[3];  const float* be1 = (const float*)d_in[4];
  const float* W1a = (const float*)d_in[5];  const float* b1a = (const float*)d_in[6];
  const float* W1b = (const float*)d_in[7];  const float* b1b = (const float*)d_in[8];
  const float* We2 = (const float*)d_in[9];  const float* be2 = (const float*)d_in[10];
  const float* W2a = (const float*)d_in[11]; const float* b2a = (const float*)d_in[12];
  const float* W2b = (const float*)d_in[13]; const float* b2b = (const float*)d_in[14];
  const float* Wn1 = (const float*)d_in[15]; const float* bn1 = (const float*)d_in[16];
  const float* Wn2 = (const float*)d_in[17]; const float* bn2 = (const float*)d_in[18];
  const float* Ws1 = (const float*)d_in[19]; const float* bs1 = (const float*)d_in[20];
  const float* Ws2 = (const float*)d_in[21]; const float* bs2 = (const float*)d_in[22];
  const float* Wt1 = (const float*)d_in[23]; const float* bt1 = (const float*)d_in[24];
  const float* Wt2 = (const float*)d_in[25]; const float* bt2 = (const float*)d_in[26];

  const int N = in_sizes[0] / 32;
  const int E = in_sizes[1] / 16;
  const int* src = ei;
  const int* dst = ei + E;

  char* ws = (char*)d_ws;
  size_t off = 0;
  auto alloc = [&](size_t bytes) -> char* {
    char* p = ws + off;
    off = (off + bytes + 255) & ~(size_t)255;
    return p;
  };
  float* h1     = (float*)alloc((size_t)N * 64 * 4);
  float* aggr   = (float*)alloc((size_t)N * 64 * 4);
  float* gsum   = (float*)alloc(256);
  int*   count  = (int*)alloc((size_t)(N + 1) * 4);
  int*   start  = (int*)alloc((size_t)(N + 1) * 4);
  int*   cursor = (int*)alloc((size_t)(N + 1) * 4);
  int*   bsum   = (int*)alloc(4096);
  int*   perm   = (int*)alloc((size_t)E * 4);
  const size_t base_need = off;
  int*   srcs = (int*)alloc((size_t)E * 4);
  float* eas  = (float*)alloc((size_t)E * 16 * 4);
  const size_t mat_need = off;

  const int mode = (ws_size >= mat_need) ? 2 : (ws_size >= base_need) ? 1 : 0;

  hipMemsetAsync(gsum, 0, 256, stream);

  if (mode == 0) {
    hipMemsetAsync(aggr, 0, (size_t)N * 32 * 4, stream);
    k_edge1<<<2048, 256, 0, stream>>>(x, ea, src, dst, We1, be1, aggr, E);
    k_node1<<<2048, 256, 0, stream>>>(x, aggr, W1a, b1a, W1b, b1b, h1, N);
    hipMemsetAsync(aggr, 0, (size_t)N * 64 * 4, stream);
    k_edge2<<<2048, 256, 0, stream>>>(h1, ea, src, dst, We2, be2, aggr, E);
  } else {
    const int M = N + 1;
    const int nb = (M + 1023) / 1024;
    const int egrid = min((E + 255) / 256, 8192);
    hipMemsetAsync(count, 0, (size_t)M * 4, stream);
    k_hist<<<egrid, 256, 0, stream>>>(dst, count, E);
    k_scan1<<<nb, 256, 0, stream>>>(count, start, bsum, M);
    k_scan2<<<1, 64, 0, stream>>>(bsum, nb);
    k_scan3<<<(M + 255) / 256, 256, 0, stream>>>(start, cursor, bsum, M);
    if (mode == 2) {
      k_scatter4<<<8192, 256, 0, stream>>>(src, dst, (const float4*)ea,
                                           cursor, srcs, (float4*)eas, E);
      k_agg1<true><<<2048, 256, 0, stream>>>(x, eas, srcs, perm, start, We1, be1, aggr, N);
      k_node1<<<2048, 256, 0, stream>>>(x, aggr, W1a, b1a, W1b, b1b, h1, N);
      k_agg2<true><<<2048, 256, 0, stream>>>(h1, eas, srcs, perm, start, We2, be2, aggr, N);
    } else {
      k_scatter_perm<<<egrid, 256, 0, stream>>>(dst, cursor, perm, E);
      k_agg1<false><<<2048, 256, 0, stream>>>(x, ea, src, perm, start, We1, be1, aggr, N);
      k_node1<<<2048, 256, 0, stream>>>(x, aggr, W1a, b1a, W1b, b1b, h1, N);
      k_agg2<false><<<2048, 256, 0, stream>>>(h1, ea, src, perm, start, We2, be2, aggr, N);
    }
  }

  k_node2<<<2048, 256, 0, stream>>>(h1, aggr, W2a, b2a, W2b, b2b, gsum, N);
  k_head<<<1, 256, 0, stream>>>(gsum, Wn1, bn1, Wn2, bn2, Ws1, bs1, Ws2, bs2,
                                Wt1, bt1, Wt2, bt2, (float*)d_out, 1.f / (float)N);
}

// Round 4
// 1159.147 us; speedup vs baseline: 1.3860x; 1.2808x over previous
//
#include <hip/hip_runtime.h>
#include <math.h>

// ---------------------------------------------------------------------------
// GINE 2-layer GNN, N=100K nodes (D 32->64->64), E=3.2M edges, ED=16.
// Round 4: the edge pass was DS-pipe-bound (16 shfl broadcasts/edge ->
// ds_swizzle on the shared LDS pipe, ~600us floor across 3 structures).
// New agg kernels: each lane loads the full ea row itself via broadcast
// float4 loads (wave-uniform address -> 1 transaction) and does pure-VGPR
// FMAs. Zero cross-lane ops in the inner loop.
// ---------------------------------------------------------------------------

#define IMIN(a, b) ((a) < (b) ? (a) : (b))

// ============================ sort pipeline ================================

__global__ __launch_bounds__(256) void k_hist(
    const int* __restrict__ dst, int* __restrict__ count, int E)
{
  for (int e = blockIdx.x * blockDim.x + threadIdx.x; e < E;
       e += gridDim.x * blockDim.x)
    atomicAdd(&count[dst[e]], 1);
}

__global__ __launch_bounds__(256) void k_scan1(
    const int* __restrict__ cnt, int* __restrict__ exc,
    int* __restrict__ bsum, int M)
{
  __shared__ int wtot[4];
  const int t = threadIdx.x, lane = t & 63, wv = t >> 6;
  const int base = blockIdx.x * 1024 + t * 4;
  const int v0 = (base + 0 < M) ? cnt[base + 0] : 0;
  const int v1 = (base + 1 < M) ? cnt[base + 1] : 0;
  const int v2 = (base + 2 < M) ? cnt[base + 2] : 0;
  const int v3 = (base + 3 < M) ? cnt[base + 3] : 0;
  const int tsum = v0 + v1 + v2 + v3;
  int x = tsum;
#pragma unroll
  for (int off = 1; off < 64; off <<= 1) {
    const int y = __shfl_up(x, off, 64);
    if (lane >= off) x += y;
  }
  if (lane == 63) wtot[wv] = x;
  __syncthreads();
  int woff = 0;
#pragma unroll
  for (int w = 0; w < 4; ++w)
    if (w < wv) woff += wtot[w];
  int run = woff + x - tsum;
  if (base + 0 < M) exc[base + 0] = run;
  run += v0;
  if (base + 1 < M) exc[base + 1] = run;
  run += v1;
  if (base + 2 < M) exc[base + 2] = run;
  run += v2;
  if (base + 3 < M) exc[base + 3] = run;
  if (t == 255) bsum[blockIdx.x] = woff + x;
}

__global__ void k_scan2(int* __restrict__ bsum, int nb)
{
  if (threadIdx.x == 0) {
    int r = 0;
    for (int i = 0; i < nb; ++i) { const int t = bsum[i]; bsum[i] = r; r += t; }
  }
}

__global__ __launch_bounds__(256) void k_scan3(
    int* __restrict__ start, int* __restrict__ cursor,
    const int* __restrict__ bsum, int M)
{
  for (int i = blockIdx.x * blockDim.x + threadIdx.x; i < M;
       i += gridDim.x * blockDim.x) {
    const int s = start[i] + bsum[i >> 10];
    start[i] = s;
    cursor[i] = s;
  }
}

// 4 threads per edge: leader grabs slot, all 4 move one float4 each.
__global__ __launch_bounds__(256) void k_scatter4(
    const int* __restrict__ src, const int* __restrict__ dst,
    const float4* __restrict__ ea4, int* __restrict__ cursor,
    int* __restrict__ srcs, float4* __restrict__ eas, int E)
{
  const long tid0 = (long)blockIdx.x * blockDim.x + threadIdx.x;
  const long stride = (long)gridDim.x * blockDim.x;
  const int sub = threadIdx.x & 3;
  const long total = (long)E * 4;
  for (long t = tid0; t < total; t += stride) {
    const int e = (int)(t >> 2);
    int pos = 0;
    if (sub == 0) pos = atomicAdd(&cursor[dst[e]], 1);
    pos = __shfl(pos, 0, 4);
    if (sub == 0) srcs[pos] = src[e];
    eas[(size_t)pos * 4 + sub] = ea4[(size_t)e * 4 + sub];
  }
}

__global__ __launch_bounds__(256) void k_scatter_perm(
    const int* __restrict__ dst, int* __restrict__ cursor,
    int* __restrict__ perm, int E)
{
  for (int e = blockIdx.x * blockDim.x + threadIdx.x; e < E;
       e += gridDim.x * blockDim.x) {
    const int pos = atomicAdd(&cursor[dst[e]], 1);
    perm[pos] = e;
  }
}

// ===================== fused edge-embed + aggregate ========================
// No cross-lane ops: every lane loads the edge's full ea row (wave-uniform
// address -> broadcast transaction) and FMAs against its own We column.

template <bool MAT>
__global__ __launch_bounds__(256, 4) void k_agg2(
    const float* __restrict__ h1, const float* __restrict__ EA,
    const int* __restrict__ SRCS, const int* __restrict__ perm,
    const int* __restrict__ start, const float* __restrict__ We,
    const float* __restrict__ be, float* __restrict__ aggr, int N)
{
  const int lane = threadIdx.x & 63;
  float wcol[16];
#pragma unroll
  for (int k = 0; k < 16; ++k) wcol[k] = We[k * 64 + lane];
  const float bias = be[lane];
  const float4* EA4 = (const float4*)EA;
  const int wid = (blockIdx.x * blockDim.x + threadIdx.x) >> 6;
  const int nw = (gridDim.x * blockDim.x) >> 6;
  for (int d = wid; d < N; d += nw) {
    const int beg = __builtin_amdgcn_readfirstlane(start[d]);
    const int end = __builtin_amdgcn_readfirstlane(start[d + 1]);
    float acc = 0.f;
    if (beg < end) {
      const int em1 = end - 1;
      // prefetch srcs for block 0
      int s0 = SRCS[MAT ? beg : perm[beg]];
      int s1, s2, s3;
      { const int c1 = IMIN(beg + 1, em1); s1 = SRCS[MAT ? c1 : perm[c1]]; }
      { const int c2 = IMIN(beg + 2, em1); s2 = SRCS[MAT ? c2 : perm[c2]]; }
      { const int c3 = IMIN(beg + 3, em1); s3 = SRCS[MAT ? c3 : perm[c3]]; }
      for (int i = beg; i < end; i += 4) {
        const int i1 = IMIN(i + 1, em1), i2 = IMIN(i + 2, em1), i3 = IMIN(i + 3, em1);
        const int a0 = MAT ? i : perm[i];
        const int a1 = MAT ? i1 : perm[i1];
        const int a2 = MAT ? i2 : perm[i2];
        const int a3 = MAT ? i3 : perm[i3];
        // broadcast ea loads: same address across all 64 lanes
        float4 ev0[4], ev1[4], ev2[4], ev3[4];
#pragma unroll
        for (int c = 0; c < 4; ++c) {
          ev0[c] = EA4[(size_t)a0 * 4 + c];
          ev1[c] = EA4[(size_t)a1 * 4 + c];
          ev2[c] = EA4[(size_t)a2 * 4 + c];
          ev3[c] = EA4[(size_t)a3 * 4 + c];
        }
        // coalesced gathers (srcs from prefetch)
        const float hv0 = h1[(size_t)s0 * 64 + lane];
        const float hv1 = h1[(size_t)s1 * 64 + lane];
        const float hv2 = h1[(size_t)s2 * 64 + lane];
        const float hv3 = h1[(size_t)s3 * 64 + lane];
        // prefetch next block's srcs
        const int inx = i + 4;
        int t0 = s0, t1 = s1, t2 = s2, t3 = s3;
        if (inx < end) {
          const int f1 = IMIN(inx + 1, em1), f2 = IMIN(inx + 2, em1), f3 = IMIN(inx + 3, em1);
          t0 = SRCS[MAT ? inx : perm[inx]];
          t1 = SRCS[MAT ? f1 : perm[f1]];
          t2 = SRCS[MAT ? f2 : perm[f2]];
          t3 = SRCS[MAT ? f3 : perm[f3]];
        }
        // four independent pure-VGPR FMA chains
        float m0 = bias, m1 = bias, m2 = bias, m3 = bias;
#pragma unroll
        for (int c = 0; c < 4; ++c) {
          m0 = fmaf(ev0[c].x, wcol[4 * c + 0], m0);
          m0 = fmaf(ev0[c].y, wcol[4 * c + 1], m0);
          m0 = fmaf(ev0[c].z, wcol[4 * c + 2], m0);
          m0 = fmaf(ev0[c].w, wcol[4 * c + 3], m0);
          m1 = fmaf(ev1[c].x, wcol[4 * c + 0], m1);
          m1 = fmaf(ev1[c].y, wcol[4 * c + 1], m1);
          m1 = fmaf(ev1[c].z, wcol[4 * c + 2], m1);
          m1 = fmaf(ev1[c].w, wcol[4 * c + 3], m1);
          m2 = fmaf(ev2[c].x, wcol[4 * c + 0], m2);
          m2 = fmaf(ev2[c].y, wcol[4 * c + 1], m2);
          m2 = fmaf(ev2[c].z, wcol[4 * c + 2], m2);
          m2 = fmaf(ev2[c].w, wcol[4 * c + 3], m2);
          m3 = fmaf(ev3[c].x, wcol[4 * c + 0], m3);
          m3 = fmaf(ev3[c].y, wcol[4 * c + 1], m3);
          m3 = fmaf(ev3[c].z, wcol[4 * c + 2], m3);
          m3 = fmaf(ev3[c].w, wcol[4 * c + 3], m3);
        }
        acc += fmaxf(hv0 + m0, 0.f);
        acc += (i + 1 < end) ? fmaxf(hv1 + m1, 0.f) : 0.f;
        acc += (i + 2 < end) ? fmaxf(hv2 + m2, 0.f) : 0.f;
        acc += (i + 3 < end) ? fmaxf(hv3 + m3, 0.f) : 0.f;
        s0 = t0; s1 = t1; s2 = t2; s3 = t3;
      }
    }
    aggr[(size_t)d * 64 + lane] = acc;
  }
}

template <bool MAT>
__global__ __launch_bounds__(256, 4) void k_agg1(
    const float* __restrict__ x, const float* __restrict__ EA,
    const int* __restrict__ SRCS, const int* __restrict__ perm,
    const int* __restrict__ start, const float* __restrict__ We,
    const float* __restrict__ be, float* __restrict__ aggr, int N)
{
  const int lane = threadIdx.x & 63;
  const int j = lane & 31;   // output dim
  const int p = lane >> 5;   // half-wave edge parity
  float wcol[16];
#pragma unroll
  for (int k = 0; k < 16; ++k) wcol[k] = We[k * 32 + j];
  const float bias = be[j];
  const float4* EA4 = (const float4*)EA;
  const int wid = (blockIdx.x * blockDim.x + threadIdx.x) >> 6;
  const int nw = (gridDim.x * blockDim.x) >> 6;
  for (int d = wid; d < N; d += nw) {
    const int beg = __builtin_amdgcn_readfirstlane(start[d]);
    const int end = __builtin_amdgcn_readfirstlane(start[d + 1]);
    float acc = 0.f;
    if (beg < end) {
      const int em1 = end - 1;
      int sp;
      { const int c = IMIN(beg + p, em1); sp = SRCS[MAT ? c : perm[c]]; }
      for (int i = beg; i < end; i += 2) {
        const int ic = IMIN(i + p, em1);
        const int a = MAT ? ic : perm[ic];
        float4 ev[4];
#pragma unroll
        for (int c = 0; c < 4; ++c) ev[c] = EA4[(size_t)a * 4 + c];
        const float xv = x[(size_t)sp * 32 + j];
        // prefetch next pair's src
        const int inx = i + 2;
        int tp = sp;
        if (inx < end) {
          const int fc = IMIN(inx + p, em1);
          tp = SRCS[MAT ? fc : perm[fc]];
        }
        float m = bias;
#pragma unroll
        for (int c = 0; c < 4; ++c) {
          m = fmaf(ev[c].x, wcol[4 * c + 0], m);
          m = fmaf(ev[c].y, wcol[4 * c + 1], m);
          m = fmaf(ev[c].z, wcol[4 * c + 2], m);
          m = fmaf(ev[c].w, wcol[4 * c + 3], m);
        }
        acc += (i + p < end) ? fmaxf(xv + m, 0.f) : 0.f;
        sp = tp;
      }
    }
    acc += __shfl(acc, lane ^ 32, 64);  // combine halves (once per node)
    if (lane < 32) aggr[(size_t)d * 32 + j] = acc;
  }
}

// ===================== legacy atomic path (ws fallback) ====================

__global__ __launch_bounds__(256) void k_edge1(
    const float* __restrict__ x, const float* __restrict__ ea,
    const int* __restrict__ src, const int* __restrict__ dst,
    const float* __restrict__ We, const float* __restrict__ be,
    float* __restrict__ aggr, int E)
{
  const int lane = threadIdx.x & 31;
  float wcol[16];
#pragma unroll
  for (int k = 0; k < 16; ++k) wcol[k] = We[k * 32 + lane];
  const float bias = be[lane];
  const int gid = (blockIdx.x * blockDim.x + threadIdx.x) >> 5;
  const int ngrp = (gridDim.x * blockDim.x) >> 5;
  for (int e = gid; e < E; e += ngrp) {
    const int s = src[e], d = dst[e];
    const float eav = (lane < 16) ? ea[(size_t)e * 16 + lane] : 0.f;
    float acc = bias;
#pragma unroll
    for (int k = 0; k < 16; ++k) acc = fmaf(__shfl(eav, k, 32), wcol[k], acc);
    const float m = fmaxf(x[(size_t)s * 32 + lane] + acc, 0.f);
    atomicAdd(&aggr[(size_t)d * 32 + lane], m);
  }
}

__global__ __launch_bounds__(256) void k_edge2(
    const float* __restrict__ h1, const float* __restrict__ ea,
    const int* __restrict__ src, const int* __restrict__ dst,
    const float* __restrict__ We, const float* __restrict__ be,
    float* __restrict__ aggr, int E)
{
  const int lane = threadIdx.x & 63;
  float wcol[16];
#pragma unroll
  for (int k = 0; k < 16; ++k) wcol[k] = We[k * 64 + lane];
  const float bias = be[lane];
  const int gid = (blockIdx.x * blockDim.x + threadIdx.x) >> 6;
  const int ngrp = (gridDim.x * blockDim.x) >> 6;
  for (int e = gid; e < E; e += ngrp) {
    const int s = src[e], d = dst[e];
    const float eav = (lane < 16) ? ea[(size_t)e * 16 + lane] : 0.f;
    float acc = bias;
#pragma unroll
    for (int k = 0; k < 16; ++k) acc = fmaf(__shfl(eav, k, 64), wcol[k], acc);
    const float m = fmaxf(h1[(size_t)s * 64 + lane] + acc, 0.f);
    atomicAdd(&aggr[(size_t)d * 64 + lane], m);
  }
}

// ============================ node MLPs + head =============================

__global__ __launch_bounds__(256) void k_node1(
    const float* __restrict__ x, const float* __restrict__ aggr,
    const float* __restrict__ Wa, const float* __restrict__ ba,
    const float* __restrict__ Wb, const float* __restrict__ bb,
    float* __restrict__ h1, int N)
{
  const int lane = threadIdx.x & 63;
  float wa[32], wb[64];
#pragma unroll
  for (int k = 0; k < 32; ++k) wa[k] = Wa[k * 64 + lane];
#pragma unroll
  for (int k = 0; k < 64; ++k) wb[k] = Wb[k * 64 + lane];
  const float ba_l = ba[lane], bb_l = bb[lane];
  const int wid = (blockIdx.x * blockDim.x + threadIdx.x) >> 6;
  const int nw = (gridDim.x * blockDim.x) >> 6;
  for (int n = wid; n < N; n += nw) {
    const float hp =
        (lane < 32) ? (x[(size_t)n * 32 + lane] + aggr[(size_t)n * 32 + lane]) : 0.f;
    float t = ba_l;
#pragma unroll
    for (int k = 0; k < 32; ++k) t = fmaf(__shfl(hp, k, 64), wa[k], t);
    t = fmaxf(t, 0.f);
    float h = bb_l;
#pragma unroll
    for (int k = 0; k < 64; ++k) h = fmaf(__shfl(t, k, 64), wb[k], h);
    h1[(size_t)n * 64 + lane] = h;
  }
}

__global__ __launch_bounds__(256) void k_node2(
    const float* __restrict__ h1, const float* __restrict__ aggr,
    const float* __restrict__ Wa, const float* __restrict__ ba,
    const float* __restrict__ Wb, const float* __restrict__ bb,
    float* __restrict__ gsum, int N)
{
  const int lane = threadIdx.x & 63;
  const int wv = threadIdx.x >> 6;
  float wa[64], wb[64];
#pragma unroll
  for (int k = 0; k < 64; ++k) wa[k] = Wa[k * 64 + lane];
#pragma unroll
  for (int k = 0; k < 64; ++k) wb[k] = Wb[k * 64 + lane];
  const float ba_l = ba[lane], bb_l = bb[lane];
  float psum = 0.f;
  const int wid = (blockIdx.x * blockDim.x + threadIdx.x) >> 6;
  const int nw = (gridDim.x * blockDim.x) >> 6;
  for (int n = wid; n < N; n += nw) {
    const float hp = h1[(size_t)n * 64 + lane] + aggr[(size_t)n * 64 + lane];
    float t = ba_l;
#pragma unroll
    for (int k = 0; k < 64; ++k) t = fmaf(__shfl(hp, k, 64), wa[k], t);
    t = fmaxf(t, 0.f);
    float h = bb_l;
#pragma unroll
    for (int k = 0; k < 64; ++k) h = fmaf(__shfl(t, k, 64), wb[k], h);
    psum += h;
  }
  __shared__ float red[4][64];
  red[wv][lane] = psum;
  __syncthreads();
  if (threadIdx.x < 64) {
    const float s4 = red[0][lane] + red[1][lane] + red[2][lane] + red[3][lane];
    atomicAdd(&gsum[lane], s4);
  }
}

__global__ __launch_bounds__(256) void k_head(
    const float* __restrict__ gsum,
    const float* __restrict__ Wn1, const float* __restrict__ bn1,
    const float* __restrict__ Wn2, const float* __restrict__ bn2,
    const float* __restrict__ Ws1, const float* __restrict__ bs1,
    const float* __restrict__ Ws2, const float* __restrict__ bs2,
    const float* __restrict__ Wt1, const float* __restrict__ bt1,
    const float* __restrict__ Wt2, const float* __restrict__ bt2,
    float* __restrict__ out, float invN)
{
  __shared__ float g[64], z1[256], z2[128], sa[64], tb[64];
  const int t = threadIdx.x;
  if (t < 64) g[t] = gsum[t] * invN;
  __syncthreads();
  {
    float acc = bn1[t];
    for (int k = 0; k < 64; ++k) acc = fmaf(g[k], Wn1[k * 256 + t], acc);
    z1[t] = fmaxf(acc, 0.f);
  }
  __syncthreads();
  if (t < 128) {
    float acc = bn2[t];
    for (int k = 0; k < 256; ++k) acc = fmaf(z1[k], Wn2[k * 128 + t], acc);
    z2[t] = fmaxf(acc, 0.f);
  }
  __syncthreads();
  if (t < 64) {
    float acc = bs1[t];
    for (int k = 0; k < 128; ++k) acc = fmaf(z2[k], Ws1[k * 64 + t], acc);
    sa[t] = fmaxf(acc, 0.f);
  } else if (t < 128) {
    const int j = t - 64;
    float acc = bt1[j];
    for (int k = 0; k < 128; ++k) acc = fmaf(z2[k], Wt1[k * 64 + j], acc);
    tb[j] = fmaxf(acc, 0.f);
  }
  __syncthreads();
  if (t < 64) {
    float acc = bs2[t];
    for (int k = 0; k < 64; ++k) acc = fmaf(sa[k], Ws2[k * 64 + t], acc);
    out[t] = 1.f / (1.f + __expf(-acc));
  } else if (t < 96) {
    const int j = t - 64;
    float acc = bt2[j];
    for (int k = 0; k < 64; ++k) acc = fmaf(tb[k], Wt2[k * 32 + j], acc);
    out[64 + j] = 1.f / (1.f + __expf(-acc));
  }
}

// ================================ launch ===================================

extern "C" void kernel_launch(void* const* d_in, const int* in_sizes, int n_in,
                              void* d_out, int out_size, void* d_ws, size_t ws_size,
                              hipStream_t stream)
{
  const float* x   = (const float*)d_in[0];
  const float* ea  = (const float*)d_in[1];
  const int*   ei  = (const int*)d_in[2];
  const float* We1 = (const float*)d_in[3];  const float* be1 = (const float*)d_in[4];
  const float* W1a = (const float*)d_in[5];  const float* b1a = (const float*)d_in[6];
  const float* W1b = (const float*)d_in[7];  const float* b1b = (const float*)d_in[8];
  const float* We2 = (const float*)d_in[9];  const float* be2 = (const float*)d_in[10];
  const float* W2a = (const float*)d_in[11]; const float* b2a = (const float*)d_in[12];
  const float* W2b = (const float*)d_in[13]; const float* b2b = (const float*)d_in[14];
  const float* Wn1 = (const float*)d_in[15]; const float* bn1 = (const float*)d_in[16];
  const float* Wn2 = (const float*)d_in[17]; const float* bn2 = (const float*)d_in[18];
  const float* Ws1 = (const float*)d_in[19]; const float* bs1 = (const float*)d_in[20];
  const float* Ws2 = (const float*)d_in[21]; const float* bs2 = (const float*)d_in[22];
  const float* Wt1 = (const float*)d_in[23]; const float* bt1 = (const float*)d_in[24];
  const float* Wt2 = (const float*)d_in[25]; const float* bt2 = (const float*)d_in[26];

  const int N = in_sizes[0] / 32;
  const int E = in_sizes[1] / 16;
  const int* src = ei;
  const int* dst = ei + E;

  char* ws = (char*)d_ws;
  size_t off = 0;
  auto alloc = [&](size_t bytes) -> char* {
    char* p = ws + off;
    off = (off + bytes + 255) & ~(size_t)255;
    return p;
  };
  float* h1     = (float*)alloc((size_t)N * 64 * 4);
  float* aggr   = (float*)alloc((size_t)N * 64 * 4);
  float* gsum   = (float*)alloc(256);
  int*   count  = (int*)alloc((size_t)(N + 1) * 4);
  int*   start  = (int*)alloc((size_t)(N + 1) * 4);
  int*   cursor = (int*)alloc((size_t)(N + 1) * 4);
  int*   bsum   = (int*)alloc(4096);
  int*   perm   = (int*)alloc((size_t)E * 4);
  const size_t base_need = off;
  int*   srcs = (int*)alloc((size_t)E * 4);
  float* eas  = (float*)alloc((size_t)E * 16 * 4);
  const size_t mat_need = off;

  const int mode = (ws_size >= mat_need) ? 2 : (ws_size >= base_need) ? 1 : 0;

  hipMemsetAsync(gsum, 0, 256, stream);

  if (mode == 0) {
    hipMemsetAsync(aggr, 0, (size_t)N * 32 * 4, stream);
    k_edge1<<<2048, 256, 0, stream>>>(x, ea, src, dst, We1, be1, aggr, E);
    k_node1<<<2048, 256, 0, stream>>>(x, aggr, W1a, b1a, W1b, b1b, h1, N);
    hipMemsetAsync(aggr, 0, (size_t)N * 64 * 4, stream);
    k_edge2<<<2048, 256, 0, stream>>>(h1, ea, src, dst, We2, be2, aggr, E);
  } else {
    const int M = N + 1;
    const int nb = (M + 1023) / 1024;
    const int egrid = min((E + 255) / 256, 8192);
    hipMemsetAsync(count, 0, (size_t)M * 4, stream);
    k_hist<<<egrid, 256, 0, stream>>>(dst, count, E);
    k_scan1<<<nb, 256, 0, stream>>>(count, start, bsum, M);
    k_scan2<<<1, 64, 0, stream>>>(bsum, nb);
    k_scan3<<<(M + 255) / 256, 256, 0, stream>>>(start, cursor, bsum, M);
    if (mode == 2) {
      k_scatter4<<<8192, 256, 0, stream>>>(src, dst, (const float4*)ea,
                                           cursor, srcs, (float4*)eas, E);
      k_agg1<true><<<2048, 256, 0, stream>>>(x, eas, srcs, perm, start, We1, be1, aggr, N);
      k_node1<<<2048, 256, 0, stream>>>(x, aggr, W1a, b1a, W1b, b1b, h1, N);
      k_agg2<true><<<2048, 256, 0, stream>>>(h1, eas, srcs, perm, start, We2, be2, aggr, N);
    } else {
      k_scatter_perm<<<egrid, 256, 0, stream>>>(dst, cursor, perm, E);
      k_agg1<false><<<2048, 256, 0, stream>>>(x, ea, src, perm, start, We1, be1, aggr, N);
      k_node1<<<2048, 256, 0, stream>>>(x, aggr, W1a, b1a, W1b, b1b, h1, N);
      k_agg2<false><<<2048, 256, 0, stream>>>(h1, ea, src, perm, start, We2, be2, aggr, N);
    }
  }

  k_node2<<<2048, 256, 0, stream>>>(h1, aggr, W2a, b2a, W2b, b2b, gsum, N);
  k_head<<<1, 256, 0, stream>>>(gsum, Wn1, bn1, Wn2, bn2, Ws1, bs1, Ws2, bs2,
                                Wt1, bt1, Wt2, bt2, (float*)d_out, 1.f / (float)N);
}

// Round 5
// 936.017 us; speedup vs baseline: 1.7164x; 1.2384x over previous
//
#include <hip/hip_runtime.h>
#include <math.h>

// ---------------------------------------------------------------------------
// GINE 2-layer GNN, N=100K nodes (D 32->64->64), E=3.2M edges, ED=16.
// Round 5: (a) eas stored bf16-packed (32B/edge) by the scatter -> halves
// bytes AND halves ev register footprint; (b) agg kernels get a real
// double-buffered pipeline (next-block ev/hv/src loads issued before
// sched_barrier(0), compute after) so the compiler can't fuse loads into
// uses (R4's VGPR=24 tell); (c) agg1 widened to 8 edges/iter; (d) node MLP
// t-broadcast via LDS b128 reads instead of 64 shfls.
// ---------------------------------------------------------------------------

#define IMIN(a, b) ((a) < (b) ? (a) : (b))

__device__ __forceinline__ unsigned short f2bf(float f) {
  unsigned int u = __float_as_uint(f);
  u += 0x7FFFu + ((u >> 16) & 1u);
  return (unsigned short)(u >> 16);
}
__device__ __forceinline__ float bflo(int w) {
  return __uint_as_float(((unsigned int)w) << 16);
}
__device__ __forceinline__ float bfhi(int w) {
  return __uint_as_float(((unsigned int)w) & 0xFFFF0000u);
}

// ============================ sort pipeline ================================

__global__ __launch_bounds__(256) void k_hist(
    const int* __restrict__ dst, int* __restrict__ count, int E)
{
  for (int e = blockIdx.x * blockDim.x + threadIdx.x; e < E;
       e += gridDim.x * blockDim.x)
    atomicAdd(&count[dst[e]], 1);
}

__global__ __launch_bounds__(256) void k_scan1(
    const int* __restrict__ cnt, int* __restrict__ exc,
    int* __restrict__ bsum, int M)
{
  __shared__ int wtot[4];
  const int t = threadIdx.x, lane = t & 63, wv = t >> 6;
  const int base = blockIdx.x * 1024 + t * 4;
  const int v0 = (base + 0 < M) ? cnt[base + 0] : 0;
  const int v1 = (base + 1 < M) ? cnt[base + 1] : 0;
  const int v2 = (base + 2 < M) ? cnt[base + 2] : 0;
  const int v3 = (base + 3 < M) ? cnt[base + 3] : 0;
  const int tsum = v0 + v1 + v2 + v3;
  int x = tsum;
#pragma unroll
  for (int off = 1; off < 64; off <<= 1) {
    const int y = __shfl_up(x, off, 64);
    if (lane >= off) x += y;
  }
  if (lane == 63) wtot[wv] = x;
  __syncthreads();
  int woff = 0;
#pragma unroll
  for (int w = 0; w < 4; ++w)
    if (w < wv) woff += wtot[w];
  int run = woff + x - tsum;
  if (base + 0 < M) exc[base + 0] = run;
  run += v0;
  if (base + 1 < M) exc[base + 1] = run;
  run += v1;
  if (base + 2 < M) exc[base + 2] = run;
  run += v2;
  if (base + 3 < M) exc[base + 3] = run;
  if (t == 255) bsum[blockIdx.x] = woff + x;
}

__global__ void k_scan2(int* __restrict__ bsum, int nb)
{
  if (threadIdx.x == 0) {
    int r = 0;
    for (int i = 0; i < nb; ++i) { const int t = bsum[i]; bsum[i] = r; r += t; }
  }
}

__global__ __launch_bounds__(256) void k_scan3(
    int* __restrict__ start, int* __restrict__ cursor,
    const int* __restrict__ bsum, int M)
{
  for (int i = blockIdx.x * blockDim.x + threadIdx.x; i < M;
       i += gridDim.x * blockDim.x) {
    const int s = start[i] + bsum[i >> 10];
    start[i] = s;
    cursor[i] = s;
  }
}

// 4 threads/edge: leader grabs slot; each sub converts 4 floats -> 4 bf16
// and writes 8B. Edge stride in easH: 32B (4 uint2).
__global__ __launch_bounds__(256) void k_scatter_bf(
    const int* __restrict__ src, const int* __restrict__ dst,
    const float4* __restrict__ ea4, int* __restrict__ cursor,
    int* __restrict__ srcs, uint2* __restrict__ easH, int E)
{
  const long tid0 = (long)blockIdx.x * blockDim.x + threadIdx.x;
  const long stride = (long)gridDim.x * blockDim.x;
  const int sub = threadIdx.x & 3;
  const long total = (long)E * 4;
  for (long t = tid0; t < total; t += stride) {
    const int e = (int)(t >> 2);
    int pos = 0;
    if (sub == 0) pos = atomicAdd(&cursor[dst[e]], 1);
    pos = __shfl(pos, 0, 4);
    if (sub == 0) srcs[pos] = src[e];
    const float4 v = ea4[(size_t)e * 4 + sub];
    uint2 w;
    w.x = (unsigned)f2bf(v.x) | ((unsigned)f2bf(v.y) << 16);
    w.y = (unsigned)f2bf(v.z) | ((unsigned)f2bf(v.w) << 16);
    easH[(size_t)pos * 4 + sub] = w;
  }
}

__global__ __launch_bounds__(256) void k_scatter_perm(
    const int* __restrict__ dst, int* __restrict__ cursor,
    int* __restrict__ perm, int E)
{
  for (int e = blockIdx.x * blockDim.x + threadIdx.x; e < E;
       e += gridDim.x * blockDim.x) {
    const int pos = atomicAdd(&cursor[dst[e]], 1);
    perm[pos] = e;
  }
}

// ================= fused edge-embed + aggregate (bf16 eas) =================
// Double-buffered: issue block B loads, sched_barrier(0), compute block A.

__global__ __launch_bounds__(256, 4) void k_agg2_bf(
    const float* __restrict__ h1, const int4* __restrict__ EH,
    const int* __restrict__ srcs, const int* __restrict__ start,
    const float* __restrict__ We, const float* __restrict__ be,
    float* __restrict__ aggr, int N)
{
  const int lane = threadIdx.x & 63;
  float wcol[16];
#pragma unroll
  for (int k = 0; k < 16; ++k) wcol[k] = We[k * 64 + lane];
  const float bias = be[lane];
  const int wid = (blockIdx.x * blockDim.x + threadIdx.x) >> 6;
  const int nw = (gridDim.x * blockDim.x) >> 6;
  for (int d = wid; d < N; d += nw) {
    const int beg = __builtin_amdgcn_readfirstlane(start[d]);
    const int end = __builtin_amdgcn_readfirstlane(start[d + 1]);
    float acc = 0.f;
    if (beg < end) {
      const int em1 = end - 1;
      int4 evA[4][2], evB[4][2];
      float hvA[4], hvB[4];
      int sB[4], sC[4];
      {
        int sA[4];
#pragma unroll
        for (int q = 0; q < 4; ++q) {
          const int c = IMIN(beg + q, em1);
          sA[q] = srcs[c];
          evA[q][0] = EH[(size_t)c * 2 + 0];
          evA[q][1] = EH[(size_t)c * 2 + 1];
        }
#pragma unroll
        for (int q = 0; q < 4; ++q) hvA[q] = h1[(size_t)sA[q] * 64 + lane];
#pragma unroll
        for (int q = 0; q < 4; ++q) {
          const int c = IMIN(beg + 4 + q, em1);
          sB[q] = srcs[c];
        }
      }
      for (int i = beg; i < end; i += 4) {
        const bool inB = (i + 4) < end;
        if (inB) {
#pragma unroll
          for (int q = 0; q < 4; ++q) {
            const int c = IMIN(i + 4 + q, em1);
            evB[q][0] = EH[(size_t)c * 2 + 0];
            evB[q][1] = EH[(size_t)c * 2 + 1];
          }
#pragma unroll
          for (int q = 0; q < 4; ++q) hvB[q] = h1[(size_t)sB[q] * 64 + lane];
#pragma unroll
          for (int q = 0; q < 4; ++q) {
            const int c = IMIN(i + 8 + q, em1);
            sC[q] = srcs[c];
          }
        } else {
#pragma unroll
          for (int q = 0; q < 4; ++q) {
            evB[q][0] = evA[q][0]; evB[q][1] = evA[q][1];
            hvB[q] = hvA[q]; sC[q] = sB[q];
          }
        }
        __builtin_amdgcn_sched_barrier(0);
#pragma unroll
        for (int q = 0; q < 4; ++q) {
          const int4 w0 = evA[q][0], w1 = evA[q][1];
          float m = bias;
          m = fmaf(bflo(w0.x), wcol[0],  m); m = fmaf(bfhi(w0.x), wcol[1],  m);
          m = fmaf(bflo(w0.y), wcol[2],  m); m = fmaf(bfhi(w0.y), wcol[3],  m);
          m = fmaf(bflo(w0.z), wcol[4],  m); m = fmaf(bfhi(w0.z), wcol[5],  m);
          m = fmaf(bflo(w0.w), wcol[6],  m); m = fmaf(bfhi(w0.w), wcol[7],  m);
          m = fmaf(bflo(w1.x), wcol[8],  m); m = fmaf(bfhi(w1.x), wcol[9],  m);
          m = fmaf(bflo(w1.y), wcol[10], m); m = fmaf(bfhi(w1.y), wcol[11], m);
          m = fmaf(bflo(w1.z), wcol[12], m); m = fmaf(bfhi(w1.z), wcol[13], m);
          m = fmaf(bflo(w1.w), wcol[14], m); m = fmaf(bfhi(w1.w), wcol[15], m);
          acc += (i + q < end) ? fmaxf(hvA[q] + m, 0.f) : 0.f;
        }
#pragma unroll
        for (int q = 0; q < 4; ++q) {
          evA[q][0] = evB[q][0]; evA[q][1] = evB[q][1];
          hvA[q] = hvB[q]; sB[q] = sC[q];
        }
      }
    }
    aggr[(size_t)d * 64 + lane] = acc;
  }
}

// agg1: half-wave (32 lanes) owns 4 edges per 8-edge block; 4 chains/lane.
__global__ __launch_bounds__(256, 4) void k_agg1_bf(
    const float* __restrict__ x, const int4* __restrict__ EH,
    const int* __restrict__ srcs, const int* __restrict__ start,
    const float* __restrict__ We, const float* __restrict__ be,
    float* __restrict__ aggr, int N)
{
  const int lane = threadIdx.x & 63;
  const int j = lane & 31;
  const int o = (lane >> 5) * 4;  // half-wave chain base within 8-block
  float wcol[16];
#pragma unroll
  for (int k = 0; k < 16; ++k) wcol[k] = We[k * 32 + j];
  const float bias = be[j];
  const int wid = (blockIdx.x * blockDim.x + threadIdx.x) >> 6;
  const int nw = (gridDim.x * blockDim.x) >> 6;
  for (int d = wid; d < N; d += nw) {
    const int beg = __builtin_amdgcn_readfirstlane(start[d]);
    const int end = __builtin_amdgcn_readfirstlane(start[d + 1]);
    float acc = 0.f;
    if (beg < end) {
      const int em1 = end - 1;
      int4 evA[4][2], evB[4][2];
      float hvA[4], hvB[4];
      int sB[4], sC[4];
      {
        int sA[4];
#pragma unroll
        for (int q = 0; q < 4; ++q) {
          const int c = IMIN(beg + o + q, em1);
          sA[q] = srcs[c];
          evA[q][0] = EH[(size_t)c * 2 + 0];
          evA[q][1] = EH[(size_t)c * 2 + 1];
        }
#pragma unroll
        for (int q = 0; q < 4; ++q) hvA[q] = x[(size_t)sA[q] * 32 + j];
#pragma unroll
        for (int q = 0; q < 4; ++q) {
          const int c = IMIN(beg + 8 + o + q, em1);
          sB[q] = srcs[c];
        }
      }
      for (int i = beg; i < end; i += 8) {
        const bool inB = (i + 8) < end;
        if (inB) {
#pragma unroll
          for (int q = 0; q < 4; ++q) {
            const int c = IMIN(i + 8 + o + q, em1);
            evB[q][0] = EH[(size_t)c * 2 + 0];
            evB[q][1] = EH[(size_t)c * 2 + 1];
          }
#pragma unroll
          for (int q = 0; q < 4; ++q) hvB[q] = x[(size_t)sB[q] * 32 + j];
#pragma unroll
          for (int q = 0; q < 4; ++q) {
            const int c = IMIN(i + 16 + o + q, em1);
            sC[q] = srcs[c];
          }
        } else {
#pragma unroll
          for (int q = 0; q < 4; ++q) {
            evB[q][0] = evA[q][0]; evB[q][1] = evA[q][1];
            hvB[q] = hvA[q]; sC[q] = sB[q];
          }
        }
        __builtin_amdgcn_sched_barrier(0);
#pragma unroll
        for (int q = 0; q < 4; ++q) {
          const int4 w0 = evA[q][0], w1 = evA[q][1];
          float m = bias;
          m = fmaf(bflo(w0.x), wcol[0],  m); m = fmaf(bfhi(w0.x), wcol[1],  m);
          m = fmaf(bflo(w0.y), wcol[2],  m); m = fmaf(bfhi(w0.y), wcol[3],  m);
          m = fmaf(bflo(w0.z), wcol[4],  m); m = fmaf(bfhi(w0.z), wcol[5],  m);
          m = fmaf(bflo(w0.w), wcol[6],  m); m = fmaf(bfhi(w0.w), wcol[7],  m);
          m = fmaf(bflo(w1.x), wcol[8],  m); m = fmaf(bfhi(w1.x), wcol[9],  m);
          m = fmaf(bflo(w1.y), wcol[10], m); m = fmaf(bfhi(w1.y), wcol[11], m);
          m = fmaf(bflo(w1.z), wcol[12], m); m = fmaf(bfhi(w1.z), wcol[13], m);
          m = fmaf(bflo(w1.w), wcol[14], m); m = fmaf(bfhi(w1.w), wcol[15], m);
          acc += (i + o + q < end) ? fmaxf(hvA[q] + m, 0.f) : 0.f;
        }
#pragma unroll
        for (int q = 0; q < 4; ++q) {
          evA[q][0] = evB[q][0]; evA[q][1] = evB[q][1];
          hvA[q] = hvB[q]; sB[q] = sC[q];
        }
      }
    }
    acc += __shfl(acc, lane ^ 32, 64);
    if (lane < 32) aggr[(size_t)d * 32 + j] = acc;
  }
}

// ================= mode-1 fallback (fp32 ea via perm) ======================

template <bool MAT>
__global__ __launch_bounds__(256, 4) void k_agg2(
    const float* __restrict__ h1, const float* __restrict__ EA,
    const int* __restrict__ SRCS, const int* __restrict__ perm,
    const int* __restrict__ start, const float* __restrict__ We,
    const float* __restrict__ be, float* __restrict__ aggr, int N)
{
  const int lane = threadIdx.x & 63;
  float wcol[16];
#pragma unroll
  for (int k = 0; k < 16; ++k) wcol[k] = We[k * 64 + lane];
  const float bias = be[lane];
  const float4* EA4 = (const float4*)EA;
  const int wid = (blockIdx.x * blockDim.x + threadIdx.x) >> 6;
  const int nw = (gridDim.x * blockDim.x) >> 6;
  for (int d = wid; d < N; d += nw) {
    const int beg = __builtin_amdgcn_readfirstlane(start[d]);
    const int end = __builtin_amdgcn_readfirstlane(start[d + 1]);
    float acc = 0.f;
    for (int i = beg; i < end; ++i) {
      const int a = MAT ? i : perm[i];
      const int s = SRCS[a];
      float4 ev[4];
#pragma unroll
      for (int c = 0; c < 4; ++c) ev[c] = EA4[(size_t)a * 4 + c];
      const float hv = h1[(size_t)s * 64 + lane];
      float m = bias;
#pragma unroll
      for (int c = 0; c < 4; ++c) {
        m = fmaf(ev[c].x, wcol[4 * c + 0], m);
        m = fmaf(ev[c].y, wcol[4 * c + 1], m);
        m = fmaf(ev[c].z, wcol[4 * c + 2], m);
        m = fmaf(ev[c].w, wcol[4 * c + 3], m);
      }
      acc += fmaxf(hv + m, 0.f);
    }
    aggr[(size_t)d * 64 + lane] = acc;
  }
}

template <bool MAT>
__global__ __launch_bounds__(256, 4) void k_agg1(
    const float* __restrict__ x, const float* __restrict__ EA,
    const int* __restrict__ SRCS, const int* __restrict__ perm,
    const int* __restrict__ start, const float* __restrict__ We,
    const float* __restrict__ be, float* __restrict__ aggr, int N)
{
  const int lane = threadIdx.x & 63;
  const int j = lane & 31;
  const int p = lane >> 5;
  float wcol[16];
#pragma unroll
  for (int k = 0; k < 16; ++k) wcol[k] = We[k * 32 + j];
  const float bias = be[j];
  const float4* EA4 = (const float4*)EA;
  const int wid = (blockIdx.x * blockDim.x + threadIdx.x) >> 6;
  const int nw = (gridDim.x * blockDim.x) >> 6;
  for (int d = wid; d < N; d += nw) {
    const int beg = __builtin_amdgcn_readfirstlane(start[d]);
    const int end = __builtin_amdgcn_readfirstlane(start[d + 1]);
    float acc = 0.f;
    for (int i = beg + p; i < end; i += 2) {
      const int a = MAT ? i : perm[i];
      const int s = SRCS[a];
      float4 ev[4];
#pragma unroll
      for (int c = 0; c < 4; ++c) ev[c] = EA4[(size_t)a * 4 + c];
      const float xv = x[(size_t)s * 32 + j];
      float m = bias;
#pragma unroll
      for (int c = 0; c < 4; ++c) {
        m = fmaf(ev[c].x, wcol[4 * c + 0], m);
        m = fmaf(ev[c].y, wcol[4 * c + 1], m);
        m = fmaf(ev[c].z, wcol[4 * c + 2], m);
        m = fmaf(ev[c].w, wcol[4 * c + 3], m);
      }
      acc += fmaxf(xv + m, 0.f);
    }
    acc += __shfl(acc, lane ^ 32, 64);
    if (lane < 32) aggr[(size_t)d * 32 + j] = acc;
  }
}

// ===================== legacy atomic path (mode 0) =========================

__global__ __launch_bounds__(256) void k_edge1(
    const float* __restrict__ x, const float* __restrict__ ea,
    const int* __restrict__ src, const int* __restrict__ dst,
    const float* __restrict__ We, const float* __restrict__ be,
    float* __restrict__ aggr, int E)
{
  const int lane = threadIdx.x & 31;
  float wcol[16];
#pragma unroll
  for (int k = 0; k < 16; ++k) wcol[k] = We[k * 32 + lane];
  const float bias = be[lane];
  const int gid = (blockIdx.x * blockDim.x + threadIdx.x) >> 5;
  const int ngrp = (gridDim.x * blockDim.x) >> 5;
  for (int e = gid; e < E; e += ngrp) {
    const int s = src[e], d = dst[e];
    const float eav = (lane < 16) ? ea[(size_t)e * 16 + lane] : 0.f;
    float acc = bias;
#pragma unroll
    for (int k = 0; k < 16; ++k) acc = fmaf(__shfl(eav, k, 32), wcol[k], acc);
    const float m = fmaxf(x[(size_t)s * 32 + lane] + acc, 0.f);
    atomicAdd(&aggr[(size_t)d * 32 + lane], m);
  }
}

__global__ __launch_bounds__(256) void k_edge2(
    const float* __restrict__ h1, const float* __restrict__ ea,
    const int* __restrict__ src, const int* __restrict__ dst,
    const float* __restrict__ We, const float* __restrict__ be,
    float* __restrict__ aggr, int E)
{
  const int lane = threadIdx.x & 63;
  float wcol[16];
#pragma unroll
  for (int k = 0; k < 16; ++k) wcol[k] = We[k * 64 + lane];
  const float bias = be[lane];
  const int gid = (blockIdx.x * blockDim.x + threadIdx.x) >> 6;
  const int ngrp = (gridDim.x * blockDim.x) >> 6;
  for (int e = gid; e < E; e += ngrp) {
    const int s = src[e], d = dst[e];
    const float eav = (lane < 16) ? ea[(size_t)e * 16 + lane] : 0.f;
    float acc = bias;
#pragma unroll
    for (int k = 0; k < 16; ++k) acc = fmaf(__shfl(eav, k, 64), wcol[k], acc);
    const float m = fmaxf(h1[(size_t)s * 64 + lane] + acc, 0.f);
    atomicAdd(&aggr[(size_t)d * 64 + lane], m);
  }
}

// ============================ node MLPs + head =============================

__global__ __launch_bounds__(256) void k_node1(
    const float* __restrict__ x, const float* __restrict__ aggr,
    const float* __restrict__ Wa, const float* __restrict__ ba,
    const float* __restrict__ Wb, const float* __restrict__ bb,
    float* __restrict__ h1, int N)
{
  __shared__ float tsh[4][64];
  const int lane = threadIdx.x & 63;
  const int wv = threadIdx.x >> 6;
  float wa[32], wb[64];
#pragma unroll
  for (int k = 0; k < 32; ++k) wa[k] = Wa[k * 64 + lane];
#pragma unroll
  for (int k = 0; k < 64; ++k) wb[k] = Wb[k * 64 + lane];
  const float ba_l = ba[lane], bb_l = bb[lane];
  const int wid = (blockIdx.x * blockDim.x + threadIdx.x) >> 6;
  const int nw = (gridDim.x * blockDim.x) >> 6;
  const float4* tp = (const float4*)(&tsh[wv][0]);
  for (int n = wid; n < N; n += nw) {
    const float hp =
        (lane < 32) ? (x[(size_t)n * 32 + lane] + aggr[(size_t)n * 32 + lane]) : 0.f;
    float t = ba_l;
#pragma unroll
    for (int k = 0; k < 32; ++k) t = fmaf(__shfl(hp, k, 64), wa[k], t);
    t = fmaxf(t, 0.f);
    tsh[wv][lane] = t;
    float h = bb_l;
#pragma unroll
    for (int c = 0; c < 16; ++c) {
      const float4 tv = tp[c];
      h = fmaf(tv.x, wb[4 * c + 0], h);
      h = fmaf(tv.y, wb[4 * c + 1], h);
      h = fmaf(tv.z, wb[4 * c + 2], h);
      h = fmaf(tv.w, wb[4 * c + 3], h);
    }
    h1[(size_t)n * 64 + lane] = h;
  }
}

__global__ __launch_bounds__(256) void k_node2(
    const float* __restrict__ h1, const float* __restrict__ aggr,
    const float* __restrict__ Wa, const float* __restrict__ ba,
    const float* __restrict__ Wb, const float* __restrict__ bb,
    float* __restrict__ gsum, int N)
{
  __shared__ float tsh[4][64];
  __shared__ float red[4][64];
  const int lane = threadIdx.x & 63;
  const int wv = threadIdx.x >> 6;
  float wa[64], wb[64];
#pragma unroll
  for (int k = 0; k < 64; ++k) wa[k] = Wa[k * 64 + lane];
#pragma unroll
  for (int k = 0; k < 64; ++k) wb[k] = Wb[k * 64 + lane];
  const float ba_l = ba[lane], bb_l = bb[lane];
  float psum = 0.f;
  const int wid = (blockIdx.x * blockDim.x + threadIdx.x) >> 6;
  const int nw = (gridDim.x * blockDim.x) >> 6;
  const float4* tp = (const float4*)(&tsh[wv][0]);
  for (int n = wid; n < N; n += nw) {
    const float hp = h1[(size_t)n * 64 + lane] + aggr[(size_t)n * 64 + lane];
    float t = ba_l;
#pragma unroll
    for (int k = 0; k < 64; ++k) t = fmaf(__shfl(hp, k, 64), wa[k], t);
    t = fmaxf(t, 0.f);
    tsh[wv][lane] = t;
    float h = bb_l;
#pragma unroll
    for (int c = 0; c < 16; ++c) {
      const float4 tv = tp[c];
      h = fmaf(tv.x, wb[4 * c + 0], h);
      h = fmaf(tv.y, wb[4 * c + 1], h);
      h = fmaf(tv.z, wb[4 * c + 2], h);
      h = fmaf(tv.w, wb[4 * c + 3], h);
    }
    psum += h;
  }
  red[wv][lane] = psum;
  __syncthreads();
  if (threadIdx.x < 64) {
    const float s4 = red[0][lane] + red[1][lane] + red[2][lane] + red[3][lane];
    atomicAdd(&gsum[lane], s4);
  }
}

__global__ __launch_bounds__(256) void k_head(
    const float* __restrict__ gsum,
    const float* __restrict__ Wn1, const float* __restrict__ bn1,
    const float* __restrict__ Wn2, const float* __restrict__ bn2,
    const float* __restrict__ Ws1, const float* __restrict__ bs1,
    const float* __restrict__ Ws2, const float* __restrict__ bs2,
    const float* __restrict__ Wt1, const float* __restrict__ bt1,
    const float* __restrict__ Wt2, const float* __restrict__ bt2,
    float* __restrict__ out, float invN)
{
  __shared__ float g[64], z1[256], z2[128], sa[64], tb[64];
  const int t = threadIdx.x;
  if (t < 64) g[t] = gsum[t] * invN;
  __syncthreads();
  {
    float acc = bn1[t];
    for (int k = 0; k < 64; ++k) acc = fmaf(g[k], Wn1[k * 256 + t], acc);
    z1[t] = fmaxf(acc, 0.f);
  }
  __syncthreads();
  if (t < 128) {
    float acc = bn2[t];
    for (int k = 0; k < 256; ++k) acc = fmaf(z1[k], Wn2[k * 128 + t], acc);
    z2[t] = fmaxf(acc, 0.f);
  }
  __syncthreads();
  if (t < 64) {
    float acc = bs1[t];
    for (int k = 0; k < 128; ++k) acc = fmaf(z2[k], Ws1[k * 64 + t], acc);
    sa[t] = fmaxf(acc, 0.f);
  } else if (t < 128) {
    const int j = t - 64;
    float acc = bt1[j];
    for (int k = 0; k < 128; ++k) acc = fmaf(z2[k], Wt1[k * 64 + j], acc);
    tb[j] = fmaxf(acc, 0.f);
  }
  __syncthreads();
  if (t < 64) {
    float acc = bs2[t];
    for (int k = 0; k < 64; ++k) acc = fmaf(sa[k], Ws2[k * 64 + t], acc);
    out[t] = 1.f / (1.f + __expf(-acc));
  } else if (t < 96) {
    const int j = t - 64;
    float acc = bt2[j];
    for (int k = 0; k < 64; ++k) acc = fmaf(tb[k], Wt2[k * 32 + j], acc);
    out[64 + j] = 1.f / (1.f + __expf(-acc));
  }
}

// ================================ launch ===================================

extern "C" void kernel_launch(void* const* d_in, const int* in_sizes, int n_in,
                              void* d_out, int out_size, void* d_ws, size_t ws_size,
                              hipStream_t stream)
{
  const float* x   = (const float*)d_in[0];
  const float* ea  = (const float*)d_in[1];
  const int*   ei  = (const int*)d_in[2];
  const float* We1 = (const float*)d_in[3];  const float* be1 = (const float*)d_in[4];
  const float* W1a = (const float*)d_in[5];  const float* b1a = (const float*)d_in[6];
  const float* W1b = (const float*)d_in[7];  const float* b1b = (const float*)d_in[8];
  const float* We2 = (const float*)d_in[9];  const float* be2 = (const float*)d_in[10];
  const float* W2a = (const float*)d_in[11]; const float* b2a = (const float*)d_in[12];
  const float* W2b = (const float*)d_in[13]; const float* b2b = (const float*)d_in[14];
  const float* Wn1 = (const float*)d_in[15]; const float* bn1 = (const float*)d_in[16];
  const float* Wn2 = (const float*)d_in[17]; const float* bn2 = (const float*)d_in[18];
  const float* Ws1 = (const float*)d_in[19]; const float* bs1 = (const float*)d_in[20];
  const float* Ws2 = (const float*)d_in[21]; const float* bs2 = (const float*)d_in[22];
  const float* Wt1 = (const float*)d_in[23]; const float* bt1 = (const float*)d_in[24];
  const float* Wt2 = (const float*)d_in[25]; const float* bt2 = (const float*)d_in[26];

  const int N = in_sizes[0] / 32;
  const int E = in_sizes[1] / 16;
  const int* src = ei;
  const int* dst = ei + E;

  char* ws = (char*)d_ws;
  size_t off = 0;
  auto alloc = [&](size_t bytes) -> char* {
    char* p = ws + off;
    off = (off + bytes + 255) & ~(size_t)255;
    return p;
  };
  float* h1     = (float*)alloc((size_t)N * 64 * 4);
  float* aggr   = (float*)alloc((size_t)N * 64 * 4);
  float* gsum   = (float*)alloc(256);
  int*   count  = (int*)alloc((size_t)(N + 1) * 4);
  int*   start  = (int*)alloc((size_t)(N + 1) * 4);
  int*   cursor = (int*)alloc((size_t)(N + 1) * 4);
  int*   bsum   = (int*)alloc(4096);
  int*   perm   = (int*)alloc((size_t)E * 4);
  const size_t base_need = off;
  int*   srcs = (int*)alloc((size_t)E * 4);
  char*  easH = alloc((size_t)E * 32);  // bf16-packed [E][16]
  const size_t mat_need = off;

  const int mode = (ws_size >= mat_need) ? 2 : (ws_size >= base_need) ? 1 : 0;

  hipMemsetAsync(gsum, 0, 256, stream);

  if (mode == 0) {
    hipMemsetAsync(aggr, 0, (size_t)N * 32 * 4, stream);
    k_edge1<<<2048, 256, 0, stream>>>(x, ea, src, dst, We1, be1, aggr, E);
    k_node1<<<2048, 256, 0, stream>>>(x, aggr, W1a, b1a, W1b, b1b, h1, N);
    hipMemsetAsync(aggr, 0, (size_t)N * 64 * 4, stream);
    k_edge2<<<2048, 256, 0, stream>>>(h1, ea, src, dst, We2, be2, aggr, E);
  } else {
    const int M = N + 1;
    const int nb = (M + 1023) / 1024;
    const int egrid = min((E + 255) / 256, 8192);
    hipMemsetAsync(count, 0, (size_t)M * 4, stream);
    k_hist<<<egrid, 256, 0, stream>>>(dst, count, E);
    k_scan1<<<nb, 256, 0, stream>>>(count, start, bsum, M);
    k_scan2<<<1, 64, 0, stream>>>(bsum, nb);
    k_scan3<<<(M + 255) / 256, 256, 0, stream>>>(start, cursor, bsum, M);
    if (mode == 2) {
      k_scatter_bf<<<8192, 256, 0, stream>>>(src, dst, (const float4*)ea,
                                             cursor, srcs, (uint2*)easH, E);
      k_agg1_bf<<<2048, 256, 0, stream>>>(x, (const int4*)easH, srcs, start,
                                          We1, be1, aggr, N);
      k_node1<<<2048, 256, 0, stream>>>(x, aggr, W1a, b1a, W1b, b1b, h1, N);
      k_agg2_bf<<<2048, 256, 0, stream>>>(h1, (const int4*)easH, srcs, start,
                                          We2, be2, aggr, N);
    } else {
      k_scatter_perm<<<egrid, 256, 0, stream>>>(dst, cursor, perm, E);
      k_agg1<false><<<2048, 256, 0, stream>>>(x, ea, src, perm, start, We1, be1, aggr, N);
      k_node1<<<2048, 256, 0, stream>>>(x, aggr, W1a, b1a, W1b, b1b, h1, N);
      k_agg2<false><<<2048, 256, 0, stream>>>(h1, ea, src, perm, start, We2, be2, aggr, N);
    }
  }

  k_node2<<<2048, 256, 0, stream>>>(h1, aggr, W2a, b2a, W2b, b2b, gsum, N);
  k_head<<<1, 256, 0, stream>>>(gsum, Wn1, bn1, Wn2, bn2, Ws1, bs1, Ws2, bs2,
                                Wt1, bt1, Wt2, bt2, (float*)d_out, 1.f / (float)N);
}